// Round 2
// baseline (1572.209 us; speedup 1.0000x reference)
//
#include <hip/hip_runtime.h>

typedef unsigned int u32;
typedef unsigned long long u64;

#define NN_ 6000
#define EE_ 192000
#define DD_ 512
#define KK_ 4096
#define OO_ 40
#define HSZ (1 << 19)
#define HMASK (HSZ - 1)

// order-preserving float <-> uint key (for atomic min/max on floats)
__device__ __forceinline__ u32 okey(float f) {
    u32 u = __float_as_uint(f);
    return (u & 0x80000000u) ? ~u : (u | 0x80000000u);
}
__device__ __forceinline__ float dkey(u32 u) {
    u32 b = (u & 0x80000000u) ? (u ^ 0x80000000u) : ~u;
    return __uint_as_float(b);
}
__device__ __forceinline__ u64 packKey(float v, int col) {
    return ((u64)okey(v) << 32) | (u32)(~(u32)col);
}

// ---------------- graph prep ----------------
__global__ void k_deg(const int* __restrict__ src, const int* __restrict__ dst,
                      int* __restrict__ degout, int* __restrict__ degin) {
    int e = blockIdx.x * 256 + threadIdx.x;
    if (e >= EE_) return;
    atomicAdd(&degout[src[e]], 1);
    atomicAdd(&degin[dst[e]], 1);
}

__global__ void k_rsqrtdeg(const int* __restrict__ degout, const int* __restrict__ degin,
                           float* __restrict__ rout, float* __restrict__ rin) {
    int i = blockIdx.x * 256 + threadIdx.x;
    if (i >= NN_) return;
    int doV = degout[i]; if (doV < 1) doV = 1;
    int diV = degin[i];  if (diV < 1) diV = 1;
    rout[i] = rsqrtf((float)doV);
    rin[i]  = rsqrtf((float)diV);
}

__global__ void k_scan(const int* __restrict__ cnt, int* __restrict__ offs, int n) {
    __shared__ int buf[1024];
    __shared__ int carry;
    if (threadIdx.x == 0) { carry = 0; offs[0] = 0; }
    __syncthreads();
    for (int base = 0; base < n; base += 1024) {
        int i = base + threadIdx.x;
        int v = (i < n) ? cnt[i] : 0;
        buf[threadIdx.x] = v;
        __syncthreads();
        for (int off = 1; off < 1024; off <<= 1) {
            int t = (threadIdx.x >= off) ? buf[threadIdx.x - off] : 0;
            __syncthreads();
            buf[threadIdx.x] += t;
            __syncthreads();
        }
        if (i < n) offs[i + 1] = carry + buf[threadIdx.x];
        __syncthreads();
        if (threadIdx.x == 0) carry += buf[1023];
        __syncthreads();
    }
}

__global__ void k_fill(const int* __restrict__ src, const int* __restrict__ dst,
                       const int* __restrict__ offs, int* __restrict__ cursor,
                       int* __restrict__ esrc) {
    int e = blockIdx.x * 256 + threadIdx.x;
    if (e >= EE_) return;
    int d = dst[e];
    int pos = offs[d] + atomicAdd(&cursor[d], 1);
    esrc[pos] = src[e];
}

// aggregation: one block per dst node; 256 threads x 2 features
__global__ __launch_bounds__(256) void k_agg(
    const float* __restrict__ X, const int* __restrict__ esrc,
    const int* __restrict__ offs, const float* __restrict__ rout,
    const float* __restrict__ rin, float* __restrict__ out) {
    int node = blockIdx.x;
    int beg = offs[node], end = offs[node + 1];
    float a0 = 0.f, a1 = 0.f;
    int t = threadIdx.x;
    for (int e = beg; e < end; ++e) {
        int s = esrc[e];
        float w = rout[s];
        float2 v = ((const float2*)(X + (size_t)s * DD_))[t];
        a0 = fmaf(w, v.x, a0);
        a1 = fmaf(w, v.y, a1);
    }
    float ri = rin[node];
    float2* op = (float2*)(out + (size_t)node * DD_);
    op[t] = make_float2(a0 * ri, a1 * ri);
}

// ---------------- l2 norm (rows of f32 matrix) ----------------
__global__ __launch_bounds__(256) void k_l2(const float* __restrict__ x, float* __restrict__ y) {
    int row = blockIdx.x;
    float2 v = ((const float2*)(x + (size_t)row * DD_))[threadIdx.x];
    float s = v.x * v.x + v.y * v.y;
    for (int off = 32; off; off >>= 1) s += __shfl_xor(s, off);
    __shared__ float wsum[4];
    __shared__ float tot;
    int lane = threadIdx.x & 63, wv = threadIdx.x >> 6;
    if (lane == 0) wsum[wv] = s;
    __syncthreads();
    if (threadIdx.x == 0) tot = wsum[0] + wsum[1] + wsum[2] + wsum[3];
    __syncthreads();
    float sc = 1.0f / sqrtf(tot + 1e-12f);
    ((float2*)(y + (size_t)row * DD_))[threadIdx.x] = make_float2(v.x * sc, v.y * sc);
}

// per-row codebook scale: scale[r] = 1/sqrt(sum cb[r]^2 + eps)
__global__ __launch_bounds__(256) void k_cbscale(const float* __restrict__ cb, float* __restrict__ scale) {
    int row = blockIdx.x;
    float2 v = ((const float2*)(cb + (size_t)row * DD_))[threadIdx.x];
    float s = v.x * v.x + v.y * v.y;
    for (int off = 32; off; off >>= 1) s += __shfl_xor(s, off);
    __shared__ float wsum[4];
    int lane = threadIdx.x & 63, wv = threadIdx.x >> 6;
    if (lane == 0) wsum[wv] = s;
    __syncthreads();
    if (threadIdx.x == 0) scale[row] = 1.0f / sqrtf(wsum[0] + wsum[1] + wsum[2] + wsum[3] + 1e-12f);
}

// ---------------- GEMM: C = A[f32,M,K] (opt row-gather + row-scale) @ B[f32,K,N] + bias ----------------
__global__ __launch_bounds__(256) void gemm_nn(
    const float* __restrict__ A, const int* __restrict__ gidx,
    const float* __restrict__ ascale,
    const float* __restrict__ B, const float* __restrict__ bias,
    float* __restrict__ C, int M, int Ncols, int Kdim, int relu) {
    __shared__ float As[16][68];
    __shared__ float Bs[16][68];
    int tid = threadIdx.x;
    int tx = tid & 15, ty = tid >> 4;
    int m0 = blockIdx.y * 64, n0 = blockIdx.x * 64;
    float cv[4][4] = {};
    int ar = tid >> 2;
    int ak = (tid & 3) << 2;
    int am = m0 + ar;
    const float* Arow = nullptr;
    float asc = 1.0f;
    if (am < M) {
        int r = gidx ? gidx[am] : am;
        Arow = A + (size_t)r * Kdim;
        if (ascale) asc = ascale[r];
    }
    int bk = tid >> 4;
    int bn = (tid & 15) << 2;
    for (int k0 = 0; k0 < Kdim; k0 += 16) {
        float4 av = make_float4(0.f, 0.f, 0.f, 0.f);
        if (Arow) av = *(const float4*)(Arow + k0 + ak);
        As[ak + 0][ar] = av.x * asc; As[ak + 1][ar] = av.y * asc;
        As[ak + 2][ar] = av.z * asc; As[ak + 3][ar] = av.w * asc;
        float4 bv = make_float4(0.f, 0.f, 0.f, 0.f);
        if (n0 + bn < Ncols)  // Ncols % 4 == 0, bn % 4 == 0 -> full float4 in-bounds
            bv = *(const float4*)(B + (size_t)(k0 + bk) * Ncols + n0 + bn);
        Bs[bk][bn + 0] = bv.x; Bs[bk][bn + 1] = bv.y;
        Bs[bk][bn + 2] = bv.z; Bs[bk][bn + 3] = bv.w;
        __syncthreads();
        #pragma unroll
        for (int kk = 0; kk < 16; ++kk) {
            float4 a4 = *(const float4*)&As[kk][ty << 2];
            float4 b4 = *(const float4*)&Bs[kk][tx << 2];
            float ax[4] = {a4.x, a4.y, a4.z, a4.w};
            float bx[4] = {b4.x, b4.y, b4.z, b4.w};
            #pragma unroll
            for (int i = 0; i < 4; ++i)
                #pragma unroll
                for (int j = 0; j < 4; ++j)
                    cv[i][j] = fmaf(ax[i], bx[j], cv[i][j]);
        }
        __syncthreads();
    }
    #pragma unroll
    for (int i = 0; i < 4; ++i) {
        int m = m0 + (ty << 2) + i;
        if (m >= M) continue;
        #pragma unroll
        for (int j = 0; j < 4; ++j) {
            int n = n0 + (tx << 2) + j;
            if (n >= Ncols) continue;
            float v = cv[i][j] + bias[n];
            if (relu) v = fmaxf(v, 0.f);
            C[(size_t)m * Ncols + n] = v;
        }
    }
}

// ---------------- dist GEMM: C = hn @ (cb*scale)^T, store f32 + packed argmax ----------------
__global__ __launch_bounds__(256) void gemm_dist(
    const float* __restrict__ A, const float* __restrict__ cb,
    const float* __restrict__ scale,
    float* __restrict__ distOut, u64* __restrict__ rowmax) {
    __shared__ float As[16][68];
    __shared__ float Bs[16][68];
    int tid = threadIdx.x;
    int tx = tid & 15, ty = tid >> 4;
    int m0 = blockIdx.y * 64, n0 = blockIdx.x * 64;
    float cv[4][4] = {};
    int ar = tid >> 2;
    int ak = (tid & 3) << 2;
    int am = m0 + ar;
    const float* Arow = (am < NN_) ? (A + (size_t)am * DD_) : nullptr;
    const float* Brow = cb + (size_t)(n0 + ar) * DD_;  // N=4096 exact tiles
    float bscl = scale[n0 + ar];
    for (int k0 = 0; k0 < DD_; k0 += 16) {
        float4 av = make_float4(0.f, 0.f, 0.f, 0.f);
        if (Arow) av = *(const float4*)(Arow + k0 + ak);
        As[ak + 0][ar] = av.x; As[ak + 1][ar] = av.y;
        As[ak + 2][ar] = av.z; As[ak + 3][ar] = av.w;
        float4 bv = *(const float4*)(Brow + k0 + ak);
        Bs[ak + 0][ar] = bv.x * bscl; Bs[ak + 1][ar] = bv.y * bscl;
        Bs[ak + 2][ar] = bv.z * bscl; Bs[ak + 3][ar] = bv.w * bscl;
        __syncthreads();
        #pragma unroll
        for (int kk = 0; kk < 16; ++kk) {
            float4 a4 = *(const float4*)&As[kk][ty << 2];
            float4 b4 = *(const float4*)&Bs[kk][tx << 2];
            float ax[4] = {a4.x, a4.y, a4.z, a4.w};
            float bx[4] = {b4.x, b4.y, b4.z, b4.w};
            #pragma unroll
            for (int i = 0; i < 4; ++i)
                #pragma unroll
                for (int j = 0; j < 4; ++j)
                    cv[i][j] = fmaf(ax[i], bx[j], cv[i][j]);
        }
        __syncthreads();
    }
    #pragma unroll
    for (int i = 0; i < 4; ++i) {
        int m = m0 + (ty << 2) + i;
        if (m >= NN_) continue;
        #pragma unroll
        for (int j = 0; j < 4; ++j) {
            int n = n0 + (tx << 2) + j;
            distOut[(size_t)m * KK_ + n] = cv[i][j];
        }
    }
    #pragma unroll
    for (int i = 0; i < 4; ++i) {
        int m = m0 + (ty << 2) + i;
        float best = -3.4e38f;
        int bc = 0;
        #pragma unroll
        for (int j = 0; j < 4; ++j) {
            int n = n0 + (tx << 2) + j;
            if (cv[i][j] > best) { best = cv[i][j]; bc = n; }
        }
        u64 key = packKey(best, bc);
        for (int off = 1; off < 16; off <<= 1) {
            u64 o = __shfl_xor(key, off, 16);
            if (o > key) key = o;
        }
        if (tx == 0 && m < NN_) atomicMax(&rowmax[m], key);
    }
}

__global__ void k_extract(const u64* __restrict__ rowmax, int* __restrict__ ind) {
    int i = blockIdx.x * 256 + threadIdx.x;
    if (i >= NN_) return;
    ind[i] = (int)(~(u32)(rowmax[i] & 0xFFFFFFFFull));
}

// ---------------- R-pass: reductions over QE @ QE^T, nothing stored ----------------
__global__ __launch_bounds__(256) void gemm_rpass(
    const float* __restrict__ A, float* __restrict__ gacc,
    u32* __restrict__ minKey, u32* __restrict__ maxKey) {
    __shared__ float As[16][68];
    __shared__ float Bs[16][68];
    __shared__ float red[256];
    int tid = threadIdx.x;
    int tx = tid & 15, ty = tid >> 4;
    int m0 = blockIdx.y * 64, n0 = blockIdx.x * 64;
    float cv[4][4] = {};
    int ar = tid >> 2;
    int ak = (tid & 3) << 2;
    int am = m0 + ar, bn_r = n0 + ar;
    const float* Arow = (am < NN_) ? (A + (size_t)am * DD_) : nullptr;
    const float* Brow = (bn_r < NN_) ? (A + (size_t)bn_r * DD_) : nullptr;
    for (int k0 = 0; k0 < DD_; k0 += 16) {
        float4 av = make_float4(0.f, 0.f, 0.f, 0.f);
        if (Arow) av = *(const float4*)(Arow + k0 + ak);
        As[ak + 0][ar] = av.x; As[ak + 1][ar] = av.y;
        As[ak + 2][ar] = av.z; As[ak + 3][ar] = av.w;
        float4 bv = make_float4(0.f, 0.f, 0.f, 0.f);
        if (Brow) bv = *(const float4*)(Brow + k0 + ak);
        Bs[ak + 0][ar] = bv.x; Bs[ak + 1][ar] = bv.y;
        Bs[ak + 2][ar] = bv.z; Bs[ak + 3][ar] = bv.w;
        __syncthreads();
        #pragma unroll
        for (int kk = 0; kk < 16; ++kk) {
            float4 a4 = *(const float4*)&As[kk][ty << 2];
            float4 b4 = *(const float4*)&Bs[kk][tx << 2];
            float ax[4] = {a4.x, a4.y, a4.z, a4.w};
            float bx[4] = {b4.x, b4.y, b4.z, b4.w};
            #pragma unroll
            for (int i = 0; i < 4; ++i)
                #pragma unroll
                for (int j = 0; j < 4; ++j)
                    cv[i][j] = fmaf(ax[i], bx[j], cv[i][j]);
        }
        __syncthreads();
    }
    float tsum = 0.f, tsq = 0.f, tmin = 3.4e38f, tmax = -3.4e38f;
    #pragma unroll
    for (int i = 0; i < 4; ++i) {
        int m = m0 + (ty << 2) + i;
        #pragma unroll
        for (int j = 0; j < 4; ++j) {
            int n = n0 + (tx << 2) + j;
            if (m < NN_ && n < NN_) {
                float v = cv[i][j];
                tsum += v;
                tsq = fmaf(v, v, tsq);
                tmin = fminf(tmin, v);
                tmax = fmaxf(tmax, v);
            }
        }
    }
    red[tid] = tsum; __syncthreads();
    for (int s = 128; s; s >>= 1) { if (tid < s) red[tid] += red[tid + s]; __syncthreads(); }
    if (tid == 0) atomicAdd(&gacc[0], red[0]);
    __syncthreads();
    red[tid] = tsq; __syncthreads();
    for (int s = 128; s; s >>= 1) { if (tid < s) red[tid] += red[tid + s]; __syncthreads(); }
    if (tid == 0) atomicAdd(&gacc[1], red[0]);
    __syncthreads();
    red[tid] = tmin; __syncthreads();
    for (int s = 128; s; s >>= 1) { if (tid < s) red[tid] = fminf(red[tid], red[tid + s]); __syncthreads(); }
    if (tid == 0) atomicMin(minKey, okey(red[0]));
    __syncthreads();
    red[tid] = tmax; __syncthreads();
    for (int s = 128; s; s >>= 1) { if (tid < s) red[tid] = fmaxf(red[tid], red[tid + s]); __syncthreads(); }
    if (tid == 0) atomicMax(maxKey, okey(red[0]));
}

// ---------------- losses: commit (q-h)^2 and node-rec (h-QN)^2 ----------------
__global__ __launch_bounds__(256) void k_losses(
    const float* __restrict__ h, const float* __restrict__ QN,
    const float* __restrict__ cb, const float* __restrict__ scale,
    const int* __restrict__ ind, float* __restrict__ gacc) {
    float s1 = 0.f, s2 = 0.f;
    for (int idx = blockIdx.x * 256 + threadIdx.x; idx < NN_ * DD_; idx += gridDim.x * 256) {
        int m = idx >> 9, d = idx & 511;
        int r = ind[m];
        float q = cb[(size_t)r * DD_ + d] * scale[r];
        float hv = h[idx];
        float dq = q - hv;
        s1 = fmaf(dq, dq, s1);
        float dn = hv - QN[idx];
        s2 = fmaf(dn, dn, s2);
    }
    for (int off = 32; off; off >>= 1) { s1 += __shfl_xor(s1, off); s2 += __shfl_xor(s2, off); }
    __shared__ float w1[4], w2[4];
    int lane = threadIdx.x & 63, wv = threadIdx.x >> 6;
    if (lane == 0) { w1[wv] = s1; w2[wv] = s2; }
    __syncthreads();
    if (threadIdx.x == 0) {
        atomicAdd(&gacc[2], w1[0] + w1[1] + w1[2] + w1[3]);
        atomicAdd(&gacc[3], w2[0] + w2[1] + w2[2] + w2[3]);
    }
}

// ---------------- edge multiplicity hash + sparse correction ----------------
__global__ void k_hash(const int* __restrict__ src, const int* __restrict__ dst,
                       int* __restrict__ hkey, int* __restrict__ hcnt) {
    int e = blockIdx.x * 256 + threadIdx.x;
    if (e >= EE_) return;
    int key = dst[e] * NN_ + src[e];
    u32 h = ((u32)key * 2654435761u) & HMASK;
    while (true) {
        int old = atomicCAS(&hkey[h], -1, key);
        if (old == -1 || old == key) { atomicAdd(&hcnt[h], 1); break; }
        h = (h + 1) & HMASK;
    }
}

__global__ __launch_bounds__(256) void k_corr(
    const int* __restrict__ hkey, const int* __restrict__ hcnt,
    const float* __restrict__ QE, float* __restrict__ gacc) {
    int lane = threadIdx.x & 63, wv = threadIdx.x >> 6;
    int base = blockIdx.x * 256 + wv * 64;
    float m2 = 0.f, mr = 0.f, ms = 0.f;
    for (int s = base; s < base + 64; ++s) {
        int key = hkey[s];
        if (key < 0) continue;
        int cnt = hcnt[s];
        int dN = key / NN_;
        int sN = key - dN * NN_;
        const float* x = QE + (size_t)dN * DD_;
        const float* y = QE + (size_t)sN * DD_;
        float dot = 0.f;
        #pragma unroll
        for (int j = 0; j < 8; ++j) dot = fmaf(x[lane + j * 64], y[lane + j * 64], dot);
        for (int off = 32; off; off >>= 1) dot += __shfl_xor(dot, off);
        if (lane == 0) {
            float c = (float)cnt;
            m2 = fmaf(c, c, m2);
            mr = fmaf(c, dot, mr);
            ms += c;
        }
    }
    __shared__ float c1[4], c2[4], c3[4];
    if (lane == 0) { c1[wv] = m2; c2[wv] = mr; c3[wv] = ms; }
    __syncthreads();
    if (threadIdx.x == 0) {
        atomicAdd(&gacc[4], c1[0] + c1[1] + c1[2] + c1[3]);
        atomicAdd(&gacc[5], c2[0] + c2[1] + c2[2] + c2[3]);
        atomicAdd(&gacc[6], c3[0] + c3[1] + c3[2] + c3[3]);
    }
}

// ---------------- final loss assembly ----------------
__global__ void k_final(const float* __restrict__ gacc, const u32* __restrict__ minKey,
                        const u32* __restrict__ maxKey, float* __restrict__ lossOut) {
    if (threadIdx.x != 0 || blockIdx.x != 0) return;
    double Rsum = gacc[0], Rsq = gacc[1], commitS = gacc[2], recS = gacc[3];
    double m2 = gacc[4], mr = gacc[5], ms = gacc[6];
    double mn = (double)dkey(*minKey);
    double mx = (double)dkey(*maxKey);
    double den = mx - mn;
    double NN2 = (double)NN_ * (double)NN_;
    double sum_aq2 = (Rsq - 2.0 * mn * Rsum + NN2 * mn * mn) / (den * den);
    double sum_maq = (mr - mn * ms) / den;
    double total = sum_aq2 + m2 - 2.0 * sum_maq;
    double edge = sqrt(total / NN2);
    double commit = 0.25 * commitS / ((double)NN_ * (double)DD_);
    double rec = recS / ((double)NN_ * (double)DD_);
    *lossOut = (float)(rec + edge + commit);
}

extern "C" void kernel_launch(void* const* d_in, const int* in_sizes, int n_in,
                              void* d_out, int out_size, void* d_ws, size_t ws_size,
                              hipStream_t stream) {
    const float* feats = (const float*)d_in[0];
    const float* W1 = (const float*)d_in[1];
    const float* b1 = (const float*)d_in[2];
    const float* W2 = (const float*)d_in[3];
    const float* b2v = (const float*)d_in[4];
    const float* Wd1 = (const float*)d_in[5];
    const float* bd1 = (const float*)d_in[6];
    const float* Wd2 = (const float*)d_in[7];
    const float* bd2 = (const float*)d_in[8];
    const float* Wl = (const float*)d_in[9];
    const float* bl = (const float*)d_in[10];
    const float* cb = (const float*)d_in[11];
    const int* src = (const int*)d_in[12];
    const int* dst = (const int*)d_in[13];

    float* outF = (float*)d_out;
    float* lossOut = outF + (size_t)NN_ * OO_;     // element 240000
    float* distOut = lossOut + 1;                  // element 240001
    // dist region is written only by gemm_dist; before that, use its tail as
    // scratch for the first aggregation (16B-aligned offset).
    float* agg = outF + 240004;                    // 3.07M floats << 24.5M region

    char* w = (char*)d_ws;
    size_t off = 0;
    auto alloc = [&](size_t bytes) -> void* {
        void* p = w + off;
        off = (off + bytes + 255) & ~(size_t)255;
        return p;
    };
    // zone0: zero-init
    float* gacc = (float*)alloc(64);
    u32* maxKey = (u32*)alloc(4);
    u64* rowmax = (u64*)alloc((size_t)NN_ * 8);
    int* degin = (int*)alloc((size_t)NN_ * 4);
    int* degout = (int*)alloc((size_t)NN_ * 4);
    int* cursor = (int*)alloc((size_t)NN_ * 4);
    int* hcnt = (int*)alloc((size_t)HSZ * 4);
    size_t z0end = off;
    // zone1: 0xFF-init
    int* hkey = (int*)alloc((size_t)HSZ * 4);
    u32* minKey = (u32*)alloc(4);
    size_t z1end = off;
    // uninit scratch
    int* offs = (int*)alloc((size_t)(NN_ + 1) * 4);
    int* esrc = (int*)alloc((size_t)EE_ * 4);
    float* rin = (float*)alloc((size_t)NN_ * 4);
    float* rout = (float*)alloc((size_t)NN_ * 4);
    int* ind = (int*)alloc((size_t)NN_ * 4);
    float* scale = (float*)alloc((size_t)KK_ * 4);
    float* h = (float*)alloc((size_t)NN_ * DD_ * 4);   // h, later h2
    float* hn = (float*)alloc((size_t)NN_ * DD_ * 4);  // hn, later QN, later agg2
    float* QE = (float*)alloc((size_t)NN_ * DD_ * 4);

    hipMemsetAsync(w, 0, z0end, stream);
    hipMemsetAsync(w + z0end, 0xFF, z1end - z0end, stream);

    const int TB = 256;
    k_deg<<<(EE_ + TB - 1) / TB, TB, 0, stream>>>(src, dst, degout, degin);
    k_rsqrtdeg<<<(NN_ + TB - 1) / TB, TB, 0, stream>>>(degout, degin, rout, rin);
    k_scan<<<1, 1024, 0, stream>>>(degin, offs, NN_);
    k_fill<<<(EE_ + TB - 1) / TB, TB, 0, stream>>>(src, dst, offs, cursor, esrc);
    k_agg<<<NN_, TB, 0, stream>>>(feats, esrc, offs, rout, rin, agg);
    gemm_nn<<<dim3(8, 94), TB, 0, stream>>>(agg, nullptr, nullptr, W1, b1, h, NN_, DD_, DD_, 1);
    k_l2<<<NN_, TB, 0, stream>>>(h, hn);
    k_cbscale<<<KK_, TB, 0, stream>>>(cb, scale);
    gemm_dist<<<dim3(64, 94), TB, 0, stream>>>(hn, cb, scale, distOut, rowmax);
    k_extract<<<(NN_ + TB - 1) / TB, TB, 0, stream>>>(rowmax, ind);
    gemm_nn<<<dim3(8, 94), TB, 0, stream>>>(cb, ind, scale, Wd1, bd1, QE, NN_, DD_, DD_, 0);
    gemm_nn<<<dim3(8, 94), TB, 0, stream>>>(cb, ind, scale, Wd2, bd2, hn, NN_, DD_, DD_, 0); // QN -> hn
    k_losses<<<2048, TB, 0, stream>>>(h, hn, cb, scale, ind, gacc);
    gemm_rpass<<<dim3(94, 94), TB, 0, stream>>>(QE, gacc, minKey, maxKey);
    k_hash<<<(EE_ + TB - 1) / TB, TB, 0, stream>>>(src, dst, hkey, hcnt);
    k_corr<<<HSZ / TB, TB, 0, stream>>>(hkey, hcnt, QE, gacc);
    k_agg<<<NN_, TB, 0, stream>>>(QE, esrc, offs, rout, rin, hn);  // agg2 -> hn
    gemm_nn<<<dim3(8, 94), TB, 0, stream>>>(hn, nullptr, nullptr, W2, b2v, h, NN_, DD_, DD_, 1); // h2 -> h
    gemm_nn<<<dim3(1, 94), TB, 0, stream>>>(h, nullptr, nullptr, Wl, bl, outF, NN_, OO_, DD_, 0);
    k_final<<<1, 64, 0, stream>>>(gacc, minKey, maxKey, lossOut);
}

// Round 3
// 938.749 us; speedup vs baseline: 1.6748x; 1.6748x over previous
//
#include <hip/hip_runtime.h>

typedef unsigned int u32;
typedef unsigned long long u64;

#define NN_ 6000
#define EE_ 192000
#define DD_ 512
#define KK_ 4096
#define OO_ 40
#define HSZ (1 << 19)
#define HMASK (HSZ - 1)
#define MT_A 376   // 6016/16 m-tiles for node-sized packed arrays
#define NB_N 47    // 6016/128 blocks

typedef __bf16 bf16x8 __attribute__((ext_vector_type(8)));
typedef float f32x4 __attribute__((ext_vector_type(4)));

__device__ __forceinline__ u32 okey(float f) {
    u32 u = __float_as_uint(f);
    return (u & 0x80000000u) ? ~u : (u | 0x80000000u);
}
__device__ __forceinline__ float dkey(u32 u) {
    u32 b = (u & 0x80000000u) ? (u ^ 0x80000000u) : ~u;
    return __uint_as_float(b);
}
__device__ __forceinline__ u64 packKey(float v, int col) {
    return ((u64)okey(v) << 32) | (u32)(~(u32)col);
}
__device__ __forceinline__ unsigned short f2bf_rne(float f) {
    u32 x = __float_as_uint(f);
    u32 r = x + 0x7fffu + ((x >> 16) & 1u);
    return (unsigned short)(r >> 16);
}
__device__ __forceinline__ void gld_lds16(void* l, const void* g) {
    __builtin_amdgcn_global_load_lds(
        (const __attribute__((address_space(1))) unsigned int*)g,
        (__attribute__((address_space(3))) unsigned int*)l, 16, 0, 0);
}

// ---------------- graph prep ----------------
__global__ void k_deg(const int* __restrict__ src, const int* __restrict__ dst,
                      int* __restrict__ degout, int* __restrict__ degin) {
    int e = blockIdx.x * 256 + threadIdx.x;
    if (e >= EE_) return;
    atomicAdd(&degout[src[e]], 1);
    atomicAdd(&degin[dst[e]], 1);
}

__global__ void k_rsqrtdeg(const int* __restrict__ degout, const int* __restrict__ degin,
                           float* __restrict__ rout, float* __restrict__ rin) {
    int i = blockIdx.x * 256 + threadIdx.x;
    if (i >= NN_) return;
    int doV = degout[i]; if (doV < 1) doV = 1;
    int diV = degin[i];  if (diV < 1) diV = 1;
    rout[i] = rsqrtf((float)doV);
    rin[i]  = rsqrtf((float)diV);
}

__global__ void k_scan(const int* __restrict__ cnt, int* __restrict__ offs, int n) {
    __shared__ int buf[1024];
    __shared__ int carry;
    if (threadIdx.x == 0) { carry = 0; offs[0] = 0; }
    __syncthreads();
    for (int base = 0; base < n; base += 1024) {
        int i = base + threadIdx.x;
        int v = (i < n) ? cnt[i] : 0;
        buf[threadIdx.x] = v;
        __syncthreads();
        for (int off = 1; off < 1024; off <<= 1) {
            int t = (threadIdx.x >= off) ? buf[threadIdx.x - off] : 0;
            __syncthreads();
            buf[threadIdx.x] += t;
            __syncthreads();
        }
        if (i < n) offs[i + 1] = carry + buf[threadIdx.x];
        __syncthreads();
        if (threadIdx.x == 0) carry += buf[1023];
        __syncthreads();
    }
}

__global__ void k_fill(const int* __restrict__ src, const int* __restrict__ dst,
                       const int* __restrict__ offs, int* __restrict__ cursor,
                       int* __restrict__ esrc) {
    int e = blockIdx.x * 256 + threadIdx.x;
    if (e >= EE_) return;
    int d = dst[e];
    int pos = offs[d] + atomicAdd(&cursor[d], 1);
    esrc[pos] = src[e];
}

// aggregation: one block per dst node; 256 threads x 2 features
__global__ __launch_bounds__(256) void k_agg(
    const float* __restrict__ X, const int* __restrict__ esrc,
    const int* __restrict__ offs, const float* __restrict__ rout,
    const float* __restrict__ rin, float* __restrict__ out) {
    int node = blockIdx.x;
    int beg = offs[node], end = offs[node + 1];
    float a0 = 0.f, a1 = 0.f;
    int t = threadIdx.x;
    for (int e = beg; e < end; ++e) {
        int s = esrc[e];
        float w = rout[s];
        float2 v = ((const float2*)(X + (size_t)s * DD_))[t];
        a0 = fmaf(w, v.x, a0);
        a1 = fmaf(w, v.y, a1);
    }
    float ri = rin[node];
    float2* op = (float2*)(out + (size_t)node * DD_);
    op[t] = make_float2(a0 * ri, a1 * ri);
}

// per-row scale: scale[r] = 1/sqrt(sum row^2 + eps)  (used for codebook AND h)
__global__ __launch_bounds__(256) void k_cbscale(const float* __restrict__ cb, float* __restrict__ scale) {
    int row = blockIdx.x;
    float2 v = ((const float2*)(cb + (size_t)row * DD_))[threadIdx.x];
    float s = v.x * v.x + v.y * v.y;
    for (int off = 32; off; off >>= 1) s += __shfl_xor(s, off);
    __shared__ float wsum[4];
    int lane = threadIdx.x & 63, wv = threadIdx.x >> 6;
    if (lane == 0) wsum[wv] = s;
    __syncthreads();
    if (threadIdx.x == 0) scale[row] = 1.0f / sqrtf(wsum[0] + wsum[1] + wsum[2] + wsum[3] + 1e-12f);
}

// pack fp32 rows (optional row-scale) into MFMA fragment order, bf16 hi/lo split
// P[mt][kb][lane][j] = src[mt*16 + (lane&15)][kb*32 + (lane>>4)*8 + j] * sc
// grid: (nrows_pad/16, 4), block 256
__global__ __launch_bounds__(256) void k_pack(
    const float* __restrict__ src, const float* __restrict__ rowscale, int nrows,
    unsigned short* __restrict__ dh, unsigned short* __restrict__ dl) {
    int u = threadIdx.x >> 6, lane = threadIdx.x & 63;
    int mt = blockIdx.x, kb = blockIdx.y * 4 + u;
    int row = mt * 16 + (lane & 15);
    int k = kb * 32 + (lane >> 4) * 8;
    float vals[8] = {0.f,0.f,0.f,0.f,0.f,0.f,0.f,0.f};
    if (row < nrows) {
        float sc = rowscale ? rowscale[row] : 1.0f;
        const float4* p = (const float4*)(src + (size_t)row * DD_ + k);
        float4 a = p[0], b = p[1];
        vals[0]=a.x*sc; vals[1]=a.y*sc; vals[2]=a.z*sc; vals[3]=a.w*sc;
        vals[4]=b.x*sc; vals[5]=b.y*sc; vals[6]=b.z*sc; vals[7]=b.w*sc;
    }
    u32 hw[4], lw[4];
    #pragma unroll
    for (int j = 0; j < 4; ++j) {
        unsigned short h0 = f2bf_rne(vals[2*j]),   h1 = f2bf_rne(vals[2*j+1]);
        float hf0 = __uint_as_float((u32)h0 << 16), hf1 = __uint_as_float((u32)h1 << 16);
        unsigned short l0 = f2bf_rne(vals[2*j] - hf0), l1 = f2bf_rne(vals[2*j+1] - hf1);
        hw[j] = (u32)h0 | ((u32)h1 << 16);
        lw[j] = (u32)l0 | ((u32)l1 << 16);
    }
    size_t base = (((size_t)mt * 16 + kb) * 64 + lane) * 8;
    *(uint4*)(dh + base) = make_uint4(hw[0], hw[1], hw[2], hw[3]);
    *(uint4*)(dl + base) = make_uint4(lw[0], lw[1], lw[2], lw[3]);
}

// ---------------- MFMA GEMM, C = A . B^T via split-bf16 (hi/lo, 3 mfma) ----------
// MODE 0: dist — store C fp32 to distOut
// MODE 1: rpass — upper-triangular block grid, reduce sum/sumsq/min/max of symmetric C
template<int MODE>
__global__ __launch_bounds__(256) void gemm_mfma(
    const unsigned short* __restrict__ Ah, const unsigned short* __restrict__ Al,
    const unsigned short* __restrict__ Bh, const unsigned short* __restrict__ Bl,
    float* __restrict__ distOut,
    float* __restrict__ gacc, u32* __restrict__ minKey, u32* __restrict__ maxKey) {
    if (MODE == 1 && blockIdx.x < blockIdx.y) return;  // bj >= bi only
    __shared__ char lds[32768];  // Ah|Al|Bh|Bl tiles, 8 KB each
    int tid = threadIdx.x;
    int wave = tid >> 6, lane = tid & 63;
    int gmtA = blockIdx.y * 8, gmtB = blockIdx.x * 8;
    const unsigned short* garr; int gmt0;
    if (wave == 0)      { garr = Ah; gmt0 = gmtA; }
    else if (wave == 1) { garr = Al; gmt0 = gmtA; }
    else if (wave == 2) { garr = Bh; gmt0 = gmtB; }
    else                { garr = Bl; gmt0 = gmtB; }
    char* ldst = lds + wave * 8192;
    f32x4 acc[4][4];
    #pragma unroll
    for (int i = 0; i < 4; ++i)
        #pragma unroll
        for (int j = 0; j < 4; ++j) acc[i][j] = (f32x4){0.f, 0.f, 0.f, 0.f};
    int wm = wave >> 1, wn = wave & 1;
    for (int kb = 0; kb < 16; ++kb) {
        #pragma unroll
        for (int t = 0; t < 8; ++t) {
            const char* g = (const char*)garr + (((size_t)(gmt0 + t) * 16 + kb) * 1024) + lane * 16;
            gld_lds16(ldst + t * 1024 + lane * 16, g);
        }
        __syncthreads();
        bf16x8 a_h[4], a_l[4], b_h[4], b_l[4];
        #pragma unroll
        for (int i = 0; i < 4; ++i) {
            int at = wm * 4 + i, bt = wn * 4 + i;
            a_h[i] = *(const bf16x8*)(lds + 0     + at * 1024 + lane * 16);
            a_l[i] = *(const bf16x8*)(lds + 8192  + at * 1024 + lane * 16);
            b_h[i] = *(const bf16x8*)(lds + 16384 + bt * 1024 + lane * 16);
            b_l[i] = *(const bf16x8*)(lds + 24576 + bt * 1024 + lane * 16);
        }
        #pragma unroll
        for (int i = 0; i < 4; ++i)
            #pragma unroll
            for (int j = 0; j < 4; ++j) {
                acc[i][j] = __builtin_amdgcn_mfma_f32_16x16x32_bf16(a_h[i], b_h[j], acc[i][j], 0, 0, 0);
                acc[i][j] = __builtin_amdgcn_mfma_f32_16x16x32_bf16(a_h[i], b_l[j], acc[i][j], 0, 0, 0);
                acc[i][j] = __builtin_amdgcn_mfma_f32_16x16x32_bf16(a_l[i], b_h[j], acc[i][j], 0, 0, 0);
            }
        __syncthreads();
    }
    // C/D layout: col = lane&15, row = (lane>>4)*4 + reg
    int m_base = blockIdx.y * 128 + wm * 64;
    int n_base = blockIdx.x * 128 + wn * 64;
    int rq = lane >> 4, cc = lane & 15;
    if (MODE == 0) {
        #pragma unroll
        for (int i = 0; i < 4; ++i) {
            int m = m_base + i * 16 + rq * 4;
            if (m + 3 < 0) continue;
            #pragma unroll
            for (int j = 0; j < 4; ++j) {
                int n = n_base + j * 16 + cc;
                #pragma unroll
                for (int r = 0; r < 4; ++r) {
                    if (m + r < NN_) distOut[(size_t)(m + r) * KK_ + n] = acc[i][j][r];
                }
            }
        }
    } else {
        float tsum = 0.f, tsq = 0.f, tmin = 3.4e38f, tmax = -3.4e38f;
        #pragma unroll
        for (int i = 0; i < 4; ++i) {
            #pragma unroll
            for (int j = 0; j < 4; ++j) {
                #pragma unroll
                for (int r = 0; r < 4; ++r) {
                    int m = m_base + i * 16 + rq * 4 + r;
                    int n = n_base + j * 16 + cc;
                    if (m < NN_ && n < NN_ && n >= m) {
                        float v = acc[i][j][r];
                        float w = (n > m) ? 2.f : 1.f;
                        tsum += w * v;
                        tsq  += w * v * v;
                        tmin = fminf(tmin, v);
                        tmax = fmaxf(tmax, v);
                    }
                }
            }
        }
        float* red = (float*)lds;
        red[tid] = tsum; __syncthreads();
        for (int s = 128; s; s >>= 1) { if (tid < s) red[tid] += red[tid + s]; __syncthreads(); }
        if (tid == 0) atomicAdd(&gacc[0], red[0]);
        __syncthreads();
        red[tid] = tsq; __syncthreads();
        for (int s = 128; s; s >>= 1) { if (tid < s) red[tid] += red[tid + s]; __syncthreads(); }
        if (tid == 0) atomicAdd(&gacc[1], red[0]);
        __syncthreads();
        red[tid] = tmin; __syncthreads();
        for (int s = 128; s; s >>= 1) { if (tid < s) red[tid] = fminf(red[tid], red[tid + s]); __syncthreads(); }
        if (tid == 0) atomicMin(minKey, okey(red[0]));
        __syncthreads();
        red[tid] = tmax; __syncthreads();
        for (int s = 128; s; s >>= 1) { if (tid < s) red[tid] = fmaxf(red[tid], red[tid + s]); __syncthreads(); }
        if (tid == 0) atomicMax(maxKey, okey(red[0]));
    }
}

// exact-fp32 argmax rescue: per row, candidates within 1e-3 of bf16x2 max get exact dots
__global__ __launch_bounds__(256) void k_rescore(
    const float* __restrict__ dist, const float* __restrict__ h,
    const float* __restrict__ rnorm, const float* __restrict__ cb,
    const float* __restrict__ scale, int* __restrict__ ind) {
    int row = blockIdx.x;
    const float* dr = dist + (size_t)row * KK_;
    int tid = threadIdx.x;
    float vbuf[16];
    float lmax = -3.4e38f;
    #pragma unroll
    for (int it = 0; it < 16; ++it) {
        float v = dr[tid + it * 256];
        vbuf[it] = v;
        lmax = fmaxf(lmax, v);
    }
    for (int off = 32; off; off >>= 1) lmax = fmaxf(lmax, __shfl_xor(lmax, off));
    __shared__ float wm4[4];
    __shared__ float bmax;
    __shared__ int cnt;
    __shared__ int cand[32];
    __shared__ u64 best;
    int lane = tid & 63, wv = tid >> 6;
    if (lane == 0) wm4[wv] = lmax;
    if (tid == 0) { cnt = 0; best = 0; }
    __syncthreads();
    if (tid == 0) bmax = fmaxf(fmaxf(wm4[0], wm4[1]), fmaxf(wm4[2], wm4[3]));
    __syncthreads();
    float thr = bmax - 1e-3f;
    #pragma unroll
    for (int it = 0; it < 16; ++it) {
        if (vbuf[it] >= thr) {
            int p = atomicAdd(&cnt, 1);
            if (p < 32) cand[p] = tid + it * 256;
        }
    }
    __syncthreads();
    int nc = min(cnt, 32);
    float hr = rnorm[row];
    const float* hp = h + (size_t)row * DD_;
    for (int c = wv; c < nc; c += 4) {
        int col = cand[c];
        const float* cp = cb + (size_t)col * DD_;
        float dot = 0.f;
        #pragma unroll
        for (int j = 0; j < 8; ++j) dot = fmaf(hp[lane + j * 64], cp[lane + j * 64], dot);
        for (int off = 32; off; off >>= 1) dot += __shfl_xor(dot, off);
        if (lane == 0) atomicMax(&best, packKey(dot * hr * scale[col], col));
    }
    __syncthreads();
    if (tid == 0) ind[row] = (int)(~(u32)(best & 0xFFFFFFFFull));
}

// ---------------- fp32 GEMM: C = A (opt gather+scale) @ B + bias ----------------
__global__ __launch_bounds__(256) void gemm_nn(
    const float* __restrict__ A, const int* __restrict__ gidx,
    const float* __restrict__ ascale,
    const float* __restrict__ B, const float* __restrict__ bias,
    float* __restrict__ C, int M, int Ncols, int Kdim, int relu) {
    __shared__ float As[16][68];
    __shared__ float Bs[16][68];
    int tid = threadIdx.x;
    int tx = tid & 15, ty = tid >> 4;
    int m0 = blockIdx.y * 64, n0 = blockIdx.x * 64;
    float cv[4][4] = {};
    int ar = tid >> 2;
    int ak = (tid & 3) << 2;
    int am = m0 + ar;
    const float* Arow = nullptr;
    float asc = 1.0f;
    if (am < M) {
        int r = gidx ? gidx[am] : am;
        Arow = A + (size_t)r * Kdim;
        if (ascale) asc = ascale[r];
    }
    int bk = tid >> 4;
    int bn = (tid & 15) << 2;
    for (int k0 = 0; k0 < Kdim; k0 += 16) {
        float4 av = make_float4(0.f, 0.f, 0.f, 0.f);
        if (Arow) av = *(const float4*)(Arow + k0 + ak);
        As[ak + 0][ar] = av.x * asc; As[ak + 1][ar] = av.y * asc;
        As[ak + 2][ar] = av.z * asc; As[ak + 3][ar] = av.w * asc;
        float4 bv = make_float4(0.f, 0.f, 0.f, 0.f);
        if (n0 + bn < Ncols)
            bv = *(const float4*)(B + (size_t)(k0 + bk) * Ncols + n0 + bn);
        Bs[bk][bn + 0] = bv.x; Bs[bk][bn + 1] = bv.y;
        Bs[bk][bn + 2] = bv.z; Bs[bk][bn + 3] = bv.w;
        __syncthreads();
        #pragma unroll
        for (int kk = 0; kk < 16; ++kk) {
            float4 a4 = *(const float4*)&As[kk][ty << 2];
            float4 b4 = *(const float4*)&Bs[kk][tx << 2];
            float ax[4] = {a4.x, a4.y, a4.z, a4.w};
            float bx[4] = {b4.x, b4.y, b4.z, b4.w};
            #pragma unroll
            for (int i = 0; i < 4; ++i)
                #pragma unroll
                for (int j = 0; j < 4; ++j)
                    cv[i][j] = fmaf(ax[i], bx[j], cv[i][j]);
        }
        __syncthreads();
    }
    #pragma unroll
    for (int i = 0; i < 4; ++i) {
        int m = m0 + (ty << 2) + i;
        if (m >= M) continue;
        #pragma unroll
        for (int j = 0; j < 4; ++j) {
            int n = n0 + (tx << 2) + j;
            if (n >= Ncols) continue;
            float v = cv[i][j] + bias[n];
            if (relu) v = fmaxf(v, 0.f);
            C[(size_t)m * Ncols + n] = v;
        }
    }
}

// ---------------- losses: commit (q-h)^2 and node-rec (h-QN)^2 ----------------
__global__ __launch_bounds__(256) void k_losses(
    const float* __restrict__ h, const float* __restrict__ QN,
    const float* __restrict__ cb, const float* __restrict__ scale,
    const int* __restrict__ ind, float* __restrict__ gacc) {
    float s1 = 0.f, s2 = 0.f;
    for (int idx = blockIdx.x * 256 + threadIdx.x; idx < NN_ * DD_; idx += gridDim.x * 256) {
        int m = idx >> 9, d = idx & 511;
        int r = ind[m];
        float q = cb[(size_t)r * DD_ + d] * scale[r];
        float hv = h[idx];
        float dq = q - hv;
        s1 = fmaf(dq, dq, s1);
        float dn = hv - QN[idx];
        s2 = fmaf(dn, dn, s2);
    }
    for (int off = 32; off; off >>= 1) { s1 += __shfl_xor(s1, off); s2 += __shfl_xor(s2, off); }
    __shared__ float w1[4], w2[4];
    int lane = threadIdx.x & 63, wv = threadIdx.x >> 6;
    if (lane == 0) { w1[wv] = s1; w2[wv] = s2; }
    __syncthreads();
    if (threadIdx.x == 0) {
        atomicAdd(&gacc[2], w1[0] + w1[1] + w1[2] + w1[3]);
        atomicAdd(&gacc[3], w2[0] + w2[1] + w2[2] + w2[3]);
    }
}

// ---------------- edge multiplicity hash + sparse correction ----------------
__global__ void k_hash(const int* __restrict__ src, const int* __restrict__ dst,
                       int* __restrict__ hkey, int* __restrict__ hcnt) {
    int e = blockIdx.x * 256 + threadIdx.x;
    if (e >= EE_) return;
    int key = dst[e] * NN_ + src[e];
    u32 h = ((u32)key * 2654435761u) & HMASK;
    while (true) {
        int old = atomicCAS(&hkey[h], -1, key);
        if (old == -1 || old == key) { atomicAdd(&hcnt[h], 1); break; }
        h = (h + 1) & HMASK;
    }
}

__global__ __launch_bounds__(256) void k_corr(
    const int* __restrict__ hkey, const int* __restrict__ hcnt,
    const float* __restrict__ QE, float* __restrict__ gacc) {
    int lane = threadIdx.x & 63, wv = threadIdx.x >> 6;
    int base = blockIdx.x * 256 + wv * 64;
    float m2 = 0.f, mr = 0.f, ms = 0.f;
    for (int s = base; s < base + 64; ++s) {
        int key = hkey[s];
        if (key < 0) continue;
        int cnt = hcnt[s];
        int dN = key / NN_;
        int sN = key - dN * NN_;
        const float* x = QE + (size_t)dN * DD_;
        const float* y = QE + (size_t)sN * DD_;
        float dot = 0.f;
        #pragma unroll
        for (int j = 0; j < 8; ++j) dot = fmaf(x[lane + j * 64], y[lane + j * 64], dot);
        for (int off = 32; off; off >>= 1) dot += __shfl_xor(dot, off);
        if (lane == 0) {
            float c = (float)cnt;
            m2 = fmaf(c, c, m2);
            mr = fmaf(c, dot, mr);
            ms += c;
        }
    }
    __shared__ float c1[4], c2[4], c3[4];
    if (lane == 0) { c1[wv] = m2; c2[wv] = mr; c3[wv] = ms; }
    __syncthreads();
    if (threadIdx.x == 0) {
        atomicAdd(&gacc[4], c1[0] + c1[1] + c1[2] + c1[3]);
        atomicAdd(&gacc[5], c2[0] + c2[1] + c2[2] + c2[3]);
        atomicAdd(&gacc[6], c3[0] + c3[1] + c3[2] + c3[3]);
    }
}

// ---------------- final loss assembly ----------------
__global__ void k_final(const float* __restrict__ gacc, const u32* __restrict__ minKey,
                        const u32* __restrict__ maxKey, float* __restrict__ lossOut) {
    if (threadIdx.x != 0 || blockIdx.x != 0) return;
    double Rsum = gacc[0], Rsq = gacc[1], commitS = gacc[2], recS = gacc[3];
    double m2 = gacc[4], mr = gacc[5], ms = gacc[6];
    double mn = (double)dkey(*minKey);
    double mx = (double)dkey(*maxKey);
    double den = mx - mn;
    double NN2 = (double)NN_ * (double)NN_;
    double sum_aq2 = (Rsq - 2.0 * mn * Rsum + NN2 * mn * mn) / (den * den);
    double sum_maq = (mr - mn * ms) / den;
    double total = sum_aq2 + m2 - 2.0 * sum_maq;
    double edge = sqrt(total / NN2);
    double commit = 0.25 * commitS / ((double)NN_ * (double)DD_);
    double rec = recS / ((double)NN_ * (double)DD_);
    *lossOut = (float)(rec + edge + commit);
}

extern "C" void kernel_launch(void* const* d_in, const int* in_sizes, int n_in,
                              void* d_out, int out_size, void* d_ws, size_t ws_size,
                              hipStream_t stream) {
    const float* feats = (const float*)d_in[0];
    const float* W1 = (const float*)d_in[1];
    const float* b1 = (const float*)d_in[2];
    const float* W2 = (const float*)d_in[3];
    const float* b2v = (const float*)d_in[4];
    const float* Wd1 = (const float*)d_in[5];
    const float* bd1 = (const float*)d_in[6];
    const float* Wd2 = (const float*)d_in[7];
    const float* bd2 = (const float*)d_in[8];
    const float* Wl = (const float*)d_in[9];
    const float* bl = (const float*)d_in[10];
    const float* cb = (const float*)d_in[11];
    const int* src = (const int*)d_in[12];
    const int* dst = (const int*)d_in[13];

    float* outF = (float*)d_out;
    float* lossOut = outF + (size_t)NN_ * OO_;     // element 240000
    float* distOut = lossOut + 1;                  // element 240001
    float* agg = outF + 240004;                    // pre-dist scratch inside dist region

    char* w = (char*)d_ws;
    size_t off = 0;
    auto alloc = [&](size_t bytes) -> void* {
        void* p = w + off;
        off = (off + bytes + 255) & ~(size_t)255;
        return p;
    };
    // zone0: zero-init
    float* gacc = (float*)alloc(64);
    u32* maxKey = (u32*)alloc(4);
    int* degin = (int*)alloc((size_t)NN_ * 4);
    int* degout = (int*)alloc((size_t)NN_ * 4);
    int* cursor = (int*)alloc((size_t)NN_ * 4);
    int* hcnt = (int*)alloc((size_t)HSZ * 4);
    size_t z0end = off;
    // zone1: 0xFF-init
    int* hkey = (int*)alloc((size_t)HSZ * 4);
    u32* minKey = (u32*)alloc(4);
    size_t z1end = off;
    // uninit scratch
    int* offs = (int*)alloc((size_t)(NN_ + 1) * 4);
    int* esrc = (int*)alloc((size_t)EE_ * 4);
    float* rin = (float*)alloc((size_t)NN_ * 4);
    float* rout = (float*)alloc((size_t)NN_ * 4);
    int* ind = (int*)alloc((size_t)NN_ * 4);
    float* scale = (float*)alloc((size_t)KK_ * 4);
    float* rnorm = (float*)alloc((size_t)NN_ * 4);
    float* h = (float*)alloc((size_t)NN_ * DD_ * 4);       // h, later h2
    float* QE = (float*)alloc((size_t)NN_ * DD_ * 4);
    float* QNreg = (float*)alloc((size_t)NN_ * DD_ * 4);   // QN; earlier aliased by enp
    char*  SH = (char*)alloc((size_t)MT_A * 16 * DD_ * 4); // hnp -> QEp -> agg2

    // aliases (sequential lifetimes)
    unsigned short* enp_h = (unsigned short*)QNreg;                   // dead before QN written
    unsigned short* enp_l = enp_h + (size_t)KK_ * DD_;
    unsigned short* hnp_h = (unsigned short*)SH;                      // dead after dist
    unsigned short* hnp_l = hnp_h + (size_t)MT_A * 16 * DD_;
    unsigned short* QEp_h = (unsigned short*)SH;                      // after dist, before agg2
    unsigned short* QEp_l = QEp_h + (size_t)MT_A * 16 * DD_;
    float* agg2 = (float*)SH;                                         // after rpass

    hipMemsetAsync(w, 0, z0end, stream);
    hipMemsetAsync(w + z0end, 0xFF, z1end - z0end, stream);

    const int TB = 256;
    k_deg<<<(EE_ + TB - 1) / TB, TB, 0, stream>>>(src, dst, degout, degin);
    k_rsqrtdeg<<<(NN_ + TB - 1) / TB, TB, 0, stream>>>(degout, degin, rout, rin);
    k_scan<<<1, 1024, 0, stream>>>(degin, offs, NN_);
    k_fill<<<(EE_ + TB - 1) / TB, TB, 0, stream>>>(src, dst, offs, cursor, esrc);
    k_agg<<<NN_, TB, 0, stream>>>(feats, esrc, offs, rout, rin, agg);
    gemm_nn<<<dim3(8, 94), TB, 0, stream>>>(agg, nullptr, nullptr, W1, b1, h, NN_, DD_, DD_, 1);
    k_cbscale<<<NN_, TB, 0, stream>>>(h, rnorm);
    k_cbscale<<<KK_, TB, 0, stream>>>(cb, scale);
    k_pack<<<dim3(MT_A, 4), TB, 0, stream>>>(h, rnorm, NN_, hnp_h, hnp_l);
    k_pack<<<dim3(KK_ / 16, 4), TB, 0, stream>>>(cb, scale, KK_, enp_h, enp_l);
    gemm_mfma<0><<<dim3(KK_ / 128, NB_N), TB, 0, stream>>>(hnp_h, hnp_l, enp_h, enp_l,
                                                           distOut, nullptr, nullptr, nullptr);
    k_rescore<<<NN_, TB, 0, stream>>>(distOut, h, rnorm, cb, scale, ind);
    gemm_nn<<<dim3(8, 94), TB, 0, stream>>>(cb, ind, scale, Wd1, bd1, QE, NN_, DD_, DD_, 0);
    gemm_nn<<<dim3(8, 94), TB, 0, stream>>>(cb, ind, scale, Wd2, bd2, QNreg, NN_, DD_, DD_, 0);
    k_losses<<<2048, TB, 0, stream>>>(h, QNreg, cb, scale, ind, gacc);
    k_pack<<<dim3(MT_A, 4), TB, 0, stream>>>(QE, nullptr, NN_, QEp_h, QEp_l);
    gemm_mfma<1><<<dim3(NB_N, NB_N), TB, 0, stream>>>(QEp_h, QEp_l, QEp_h, QEp_l,
                                                      nullptr, gacc, minKey, maxKey);
    k_hash<<<(EE_ + TB - 1) / TB, TB, 0, stream>>>(src, dst, hkey, hcnt);
    k_corr<<<HSZ / TB, TB, 0, stream>>>(hkey, hcnt, QE, gacc);
    k_agg<<<NN_, TB, 0, stream>>>(QE, esrc, offs, rout, rin, agg2);
    gemm_nn<<<dim3(8, 94), TB, 0, stream>>>(agg2, nullptr, nullptr, W2, b2v, h, NN_, DD_, DD_, 1);
    gemm_nn<<<dim3(1, 94), TB, 0, stream>>>(h, nullptr, nullptr, Wl, bl, outF, NN_, OO_, DD_, 0);
    k_final<<<1, 64, 0, stream>>>(gacc, minKey, maxKey, lossOut);
}

// Round 4
// 762.516 us; speedup vs baseline: 2.0619x; 1.2311x over previous
//
#include <hip/hip_runtime.h>

typedef unsigned int u32;
typedef unsigned long long u64;

#define NN_ 6000
#define EE_ 192000
#define DD_ 512
#define KK_ 4096
#define OO_ 40
#define HSZ (1 << 19)
#define HMASK (HSZ - 1)
#define MT_A 376   // ceil(6000/16) m-tiles for node-sized packed arrays
#define NB_N 47    // 6016/128 blocks

typedef __bf16 bf16x8 __attribute__((ext_vector_type(8)));
typedef float f32x4 __attribute__((ext_vector_type(4)));

__device__ __forceinline__ u32 okey(float f) {
    u32 u = __float_as_uint(f);
    return (u & 0x80000000u) ? ~u : (u | 0x80000000u);
}
__device__ __forceinline__ float dkey(u32 u) {
    u32 b = (u & 0x80000000u) ? (u ^ 0x80000000u) : ~u;
    return __uint_as_float(b);
}
__device__ __forceinline__ u64 packKey(float v, int col) {
    return ((u64)okey(v) << 32) | (u32)(~(u32)col);
}
__device__ __forceinline__ unsigned short f2bf_rne(float f) {
    u32 x = __float_as_uint(f);
    u32 r = x + 0x7fffu + ((x >> 16) & 1u);
    return (unsigned short)(r >> 16);
}
__device__ __forceinline__ void gld_lds16(void* l, const void* g) {
    __builtin_amdgcn_global_load_lds(
        (const __attribute__((address_space(1))) unsigned int*)g,
        (__attribute__((address_space(3))) unsigned int*)l, 16, 0, 0);
}
// split 8 floats into bf16 hi/lo packed words
__device__ __forceinline__ void split8(const float* vals, uint4& hw, uint4& lw) {
    u32 h[4], l[4];
    #pragma unroll
    for (int j = 0; j < 4; ++j) {
        unsigned short h0 = f2bf_rne(vals[2*j]),   h1 = f2bf_rne(vals[2*j+1]);
        float hf0 = __uint_as_float((u32)h0 << 16), hf1 = __uint_as_float((u32)h1 << 16);
        unsigned short l0 = f2bf_rne(vals[2*j] - hf0), l1 = f2bf_rne(vals[2*j+1] - hf1);
        h[j] = (u32)h0 | ((u32)h1 << 16);
        l[j] = (u32)l0 | ((u32)l1 << 16);
    }
    hw = make_uint4(h[0], h[1], h[2], h[3]);
    lw = make_uint4(l[0], l[1], l[2], l[3]);
}

// ---------------- graph prep ----------------
__global__ void k_deg(const int* __restrict__ src, const int* __restrict__ dst,
                      int* __restrict__ degout, int* __restrict__ degin) {
    int e = blockIdx.x * 256 + threadIdx.x;
    if (e >= EE_) return;
    atomicAdd(&degout[src[e]], 1);
    atomicAdd(&degin[dst[e]], 1);
}

__global__ void k_rsqrtdeg(const int* __restrict__ degout, const int* __restrict__ degin,
                           float* __restrict__ rout, float* __restrict__ rin) {
    int i = blockIdx.x * 256 + threadIdx.x;
    if (i >= NN_) return;
    int doV = degout[i]; if (doV < 1) doV = 1;
    int diV = degin[i];  if (diV < 1) diV = 1;
    rout[i] = rsqrtf((float)doV);
    rin[i]  = rsqrtf((float)diV);
}

__global__ void k_scan(const int* __restrict__ cnt, int* __restrict__ offs, int n) {
    __shared__ int buf[1024];
    __shared__ int carry;
    if (threadIdx.x == 0) { carry = 0; offs[0] = 0; }
    __syncthreads();
    for (int base = 0; base < n; base += 1024) {
        int i = base + threadIdx.x;
        int v = (i < n) ? cnt[i] : 0;
        buf[threadIdx.x] = v;
        __syncthreads();
        for (int off = 1; off < 1024; off <<= 1) {
            int t = (threadIdx.x >= off) ? buf[threadIdx.x - off] : 0;
            __syncthreads();
            buf[threadIdx.x] += t;
            __syncthreads();
        }
        if (i < n) offs[i + 1] = carry + buf[threadIdx.x];
        __syncthreads();
        if (threadIdx.x == 0) carry += buf[1023];
        __syncthreads();
    }
}

__global__ void k_fill(const int* __restrict__ src, const int* __restrict__ dst,
                       const int* __restrict__ offs, int* __restrict__ cursor,
                       int* __restrict__ esrc) {
    int e = blockIdx.x * 256 + threadIdx.x;
    if (e >= EE_) return;
    int d = dst[e];
    int pos = offs[d] + atomicAdd(&cursor[d], 1);
    esrc[pos] = src[e];
}

// write one fp32 row (in LDS) into MFMA-packed hi/lo arrays (threads t<64)
__device__ __forceinline__ void pack_row_from_lds(
    const float* rowbuf, int node, int t,
    unsigned short* __restrict__ dh, unsigned short* __restrict__ dl) {
    int kb = t >> 2, sub = t & 3;
    int lane = sub * 16 + (node & 15);
    uint4 hw, lw;
    split8(rowbuf + t * 8, hw, lw);
    size_t base = (((size_t)(node >> 4) * 16 + kb) * 64 + lane) * 8;
    *(uint4*)(dh + base) = hw;
    *(uint4*)(dl + base) = lw;
}

// aggregation (norm='both') fused with MFMA-pack of the result
__global__ __launch_bounds__(256) void k_aggp(
    const float* __restrict__ X, const int* __restrict__ esrc,
    const int* __restrict__ offs, const float* __restrict__ rout,
    const float* __restrict__ rin,
    unsigned short* __restrict__ dh, unsigned short* __restrict__ dl) {
    __shared__ float rowbuf[512];
    int node = blockIdx.x;
    int beg = offs[node], end = offs[node + 1];
    float a0 = 0.f, a1 = 0.f;
    int t = threadIdx.x;
    for (int e = beg; e < end; ++e) {
        int s = esrc[e];
        float w = rout[s];
        float2 v = ((const float2*)(X + (size_t)s * DD_))[t];
        a0 = fmaf(w, v.x, a0);
        a1 = fmaf(w, v.y, a1);
    }
    float ri = rin[node];
    rowbuf[2 * t] = a0 * ri;
    rowbuf[2 * t + 1] = a1 * ri;
    __syncthreads();
    if (t < 64) pack_row_from_lds(rowbuf, node, t, dh, dl);
}

// aggregation + pack + unweighted-sum dot with QE row (edge-loss mr term)
__global__ __launch_bounds__(256) void k_aggd(
    const float* __restrict__ QE, const int* __restrict__ esrc,
    const int* __restrict__ offs, const float* __restrict__ rout,
    const float* __restrict__ rin,
    unsigned short* __restrict__ dh, unsigned short* __restrict__ dl,
    float* __restrict__ gacc) {
    __shared__ float rowbuf[512];
    __shared__ float wred[4];
    int node = blockIdx.x;
    int beg = offs[node], end = offs[node + 1];
    float a0 = 0.f, a1 = 0.f, u0 = 0.f, u1 = 0.f;
    int t = threadIdx.x;
    for (int e = beg; e < end; ++e) {
        int s = esrc[e];
        float w = rout[s];
        float2 v = ((const float2*)(QE + (size_t)s * DD_))[t];
        a0 = fmaf(w, v.x, a0);
        a1 = fmaf(w, v.y, a1);
        u0 += v.x;
        u1 += v.y;
    }
    float ri = rin[node];
    rowbuf[2 * t] = a0 * ri;
    rowbuf[2 * t + 1] = a1 * ri;
    float2 q = ((const float2*)(QE + (size_t)node * DD_))[t];
    float c = q.x * u0 + q.y * u1;
    for (int off = 32; off; off >>= 1) c += __shfl_xor(c, off);
    int lane = t & 63, wv = t >> 6;
    if (lane == 0) wred[wv] = c;
    __syncthreads();
    if (t < 64) pack_row_from_lds(rowbuf, node, t, dh, dl);
    if (t == 0) atomicAdd(&gacc[5], wred[0] + wred[1] + wred[2] + wred[3]);
}

// per-row scale: scale[r] = 1/sqrt(sum row^2 + eps)
__global__ __launch_bounds__(256) void k_cbscale(const float* __restrict__ cb, float* __restrict__ scale) {
    int row = blockIdx.x;
    float2 v = ((const float2*)(cb + (size_t)row * DD_))[threadIdx.x];
    float s = v.x * v.x + v.y * v.y;
    for (int off = 32; off; off >>= 1) s += __shfl_xor(s, off);
    __shared__ float wsum[4];
    int lane = threadIdx.x & 63, wv = threadIdx.x >> 6;
    if (lane == 0) wsum[wv] = s;
    __syncthreads();
    if (threadIdx.x == 0) scale[row] = 1.0f / sqrtf(wsum[0] + wsum[1] + wsum[2] + wsum[3] + 1e-12f);
}

// pack fp32 rows (opt gather + row-scale) into MFMA fragment order, bf16 hi/lo
__global__ __launch_bounds__(256) void k_pack(
    const float* __restrict__ src, const float* __restrict__ rowscale,
    const int* __restrict__ gidx, int nrows,
    unsigned short* __restrict__ dh, unsigned short* __restrict__ dl) {
    int u = threadIdx.x >> 6, lane = threadIdx.x & 63;
    int mt = blockIdx.x, kb = blockIdx.y * 4 + u;
    int gr = mt * 16 + (lane & 15);
    int k = kb * 32 + (lane >> 4) * 8;
    float vals[8] = {0.f,0.f,0.f,0.f,0.f,0.f,0.f,0.f};
    if (gr < nrows) {
        int row = gidx ? gidx[gr] : gr;
        float sc = rowscale ? rowscale[row] : 1.0f;
        const float4* p = (const float4*)(src + (size_t)row * DD_ + k);
        float4 a = p[0], b = p[1];
        vals[0]=a.x*sc; vals[1]=a.y*sc; vals[2]=a.z*sc; vals[3]=a.w*sc;
        vals[4]=b.x*sc; vals[5]=b.y*sc; vals[6]=b.z*sc; vals[7]=b.w*sc;
    }
    uint4 hw, lw;
    split8(vals, hw, lw);
    size_t base = (((size_t)mt * 16 + kb) * 64 + lane) * 8;
    *(uint4*)(dh + base) = hw;
    *(uint4*)(dl + base) = lw;
}

// transpose-pack a [512,512] weight: Bp rows = output cols
__global__ __launch_bounds__(256) void k_wpack(
    const float* __restrict__ W,
    unsigned short* __restrict__ dh, unsigned short* __restrict__ dl) {
    int u = threadIdx.x >> 6, lane = threadIdx.x & 63;
    int mt = blockIdx.x, kb = blockIdx.y * 4 + u;
    int n = mt * 16 + (lane & 15);
    int k = kb * 32 + (lane >> 4) * 8;
    float vals[8];
    #pragma unroll
    for (int j = 0; j < 8; ++j) vals[j] = W[(size_t)(k + j) * DD_ + n];
    uint4 hw, lw;
    split8(vals, hw, lw);
    size_t base = (((size_t)mt * 16 + kb) * 64 + lane) * 8;
    *(uint4*)(dh + base) = hw;
    *(uint4*)(dl + base) = lw;
}

// ---------------- MFMA GEMM, C = A . B^T via split-bf16 (hi/lo, 3 mfma) ----------
// MODE 0: dist — store C fp32 to Cout (stride KK_)
// MODE 1: rpass — upper-tri block grid, reduce sum/sumsq/min/max of symmetric C
// MODE 2: dense — store C+bias (opt relu) to Cout (stride DD_), rows < Mrows
// MODE 3: loss — accumulate sum((Ref - (C+bias))^2) into gacc[3]
template<int MODE>
__global__ __launch_bounds__(256) void gemm_mfma(
    const unsigned short* __restrict__ Ah, const unsigned short* __restrict__ Al,
    const unsigned short* __restrict__ Bh, const unsigned short* __restrict__ Bl,
    float* __restrict__ Cout, const float* __restrict__ bias,
    const float* __restrict__ Ref, int relu, int Mrows,
    float* __restrict__ gacc, u32* __restrict__ minKey, u32* __restrict__ maxKey) {
    if (MODE == 1 && blockIdx.x < blockIdx.y) return;  // bj >= bi only
    __shared__ char lds[32768];  // Ah|Al|Bh|Bl tiles, 8 KB each
    int tid = threadIdx.x;
    int wave = tid >> 6, lane = tid & 63;
    int gmtA = blockIdx.y * 8, gmtB = blockIdx.x * 8;
    const unsigned short* garr; int gmt0;
    if (wave == 0)      { garr = Ah; gmt0 = gmtA; }
    else if (wave == 1) { garr = Al; gmt0 = gmtA; }
    else if (wave == 2) { garr = Bh; gmt0 = gmtB; }
    else                { garr = Bl; gmt0 = gmtB; }
    char* ldst = lds + wave * 8192;
    f32x4 acc[4][4];
    #pragma unroll
    for (int i = 0; i < 4; ++i)
        #pragma unroll
        for (int j = 0; j < 4; ++j) acc[i][j] = (f32x4){0.f, 0.f, 0.f, 0.f};
    int wm = wave >> 1, wn = wave & 1;
    for (int kb = 0; kb < 16; ++kb) {
        #pragma unroll
        for (int t = 0; t < 8; ++t) {
            const char* g = (const char*)garr + (((size_t)(gmt0 + t) * 16 + kb) * 1024) + lane * 16;
            gld_lds16(ldst + t * 1024 + lane * 16, g);
        }
        __syncthreads();
        bf16x8 a_h[4], a_l[4], b_h[4], b_l[4];
        #pragma unroll
        for (int i = 0; i < 4; ++i) {
            int at = wm * 4 + i, bt = wn * 4 + i;
            a_h[i] = *(const bf16x8*)(lds + 0     + at * 1024 + lane * 16);
            a_l[i] = *(const bf16x8*)(lds + 8192  + at * 1024 + lane * 16);
            b_h[i] = *(const bf16x8*)(lds + 16384 + bt * 1024 + lane * 16);
            b_l[i] = *(const bf16x8*)(lds + 24576 + bt * 1024 + lane * 16);
        }
        #pragma unroll
        for (int i = 0; i < 4; ++i)
            #pragma unroll
            for (int j = 0; j < 4; ++j) {
                acc[i][j] = __builtin_amdgcn_mfma_f32_16x16x32_bf16(a_h[i], b_h[j], acc[i][j], 0, 0, 0);
                acc[i][j] = __builtin_amdgcn_mfma_f32_16x16x32_bf16(a_h[i], b_l[j], acc[i][j], 0, 0, 0);
                acc[i][j] = __builtin_amdgcn_mfma_f32_16x16x32_bf16(a_l[i], b_h[j], acc[i][j], 0, 0, 0);
            }
        __syncthreads();
    }
    // C/D layout: col = lane&15, row = (lane>>4)*4 + reg
    int m_base = blockIdx.y * 128 + wm * 64;
    int n_base = blockIdx.x * 128 + wn * 64;
    int rq = lane >> 4, cc = lane & 15;
    if (MODE == 0) {
        #pragma unroll
        for (int i = 0; i < 4; ++i) {
            int m = m_base + i * 16 + rq * 4;
            #pragma unroll
            for (int j = 0; j < 4; ++j) {
                int n = n_base + j * 16 + cc;
                #pragma unroll
                for (int r = 0; r < 4; ++r) {
                    if (m + r < NN_) Cout[(size_t)(m + r) * KK_ + n] = acc[i][j][r];
                }
            }
        }
    } else if (MODE == 2) {
        #pragma unroll
        for (int i = 0; i < 4; ++i) {
            int m = m_base + i * 16 + rq * 4;
            #pragma unroll
            for (int j = 0; j < 4; ++j) {
                int n = n_base + j * 16 + cc;
                float bv = bias[n];
                #pragma unroll
                for (int r = 0; r < 4; ++r) {
                    if (m + r < Mrows) {
                        float v = acc[i][j][r] + bv;
                        if (relu) v = fmaxf(v, 0.f);
                        Cout[(size_t)(m + r) * DD_ + n] = v;
                    }
                }
            }
        }
    } else if (MODE == 3) {
        float s = 0.f;
        #pragma unroll
        for (int i = 0; i < 4; ++i) {
            int m = m_base + i * 16 + rq * 4;
            #pragma unroll
            for (int j = 0; j < 4; ++j) {
                int n = n_base + j * 16 + cc;
                float bv = bias[n];
                #pragma unroll
                for (int r = 0; r < 4; ++r) {
                    if (m + r < Mrows) {
                        float d = Ref[(size_t)(m + r) * DD_ + n] - (acc[i][j][r] + bv);
                        s = fmaf(d, d, s);
                    }
                }
            }
        }
        float* red = (float*)lds;
        red[tid] = s; __syncthreads();
        for (int st = 128; st; st >>= 1) { if (tid < st) red[tid] += red[tid + st]; __syncthreads(); }
        if (tid == 0) atomicAdd(&gacc[3], red[0]);
    } else {
        float tsum = 0.f, tsq = 0.f, tmin = 3.4e38f, tmax = -3.4e38f;
        #pragma unroll
        for (int i = 0; i < 4; ++i) {
            #pragma unroll
            for (int j = 0; j < 4; ++j) {
                #pragma unroll
                for (int r = 0; r < 4; ++r) {
                    int m = m_base + i * 16 + rq * 4 + r;
                    int n = n_base + j * 16 + cc;
                    if (m < NN_ && n < NN_ && n >= m) {
                        float v = acc[i][j][r];
                        float w = (n > m) ? 2.f : 1.f;
                        tsum += w * v;
                        tsq  += w * v * v;
                        tmin = fminf(tmin, v);
                        tmax = fmaxf(tmax, v);
                    }
                }
            }
        }
        float* red = (float*)lds;
        red[tid] = tsum; __syncthreads();
        for (int s = 128; s; s >>= 1) { if (tid < s) red[tid] += red[tid + s]; __syncthreads(); }
        if (tid == 0) atomicAdd(&gacc[0], red[0]);
        __syncthreads();
        red[tid] = tsq; __syncthreads();
        for (int s = 128; s; s >>= 1) { if (tid < s) red[tid] += red[tid + s]; __syncthreads(); }
        if (tid == 0) atomicAdd(&gacc[1], red[0]);
        __syncthreads();
        red[tid] = tmin; __syncthreads();
        for (int s = 128; s; s >>= 1) { if (tid < s) red[tid] = fminf(red[tid], red[tid + s]); __syncthreads(); }
        if (tid == 0) atomicMin(minKey, okey(red[0]));
        __syncthreads();
        red[tid] = tmax; __syncthreads();
        for (int s = 128; s; s >>= 1) { if (tid < s) red[tid] = fmaxf(red[tid], red[tid + s]); __syncthreads(); }
        if (tid == 0) atomicMax(maxKey, okey(red[0]));
    }
}

// exact-fp32 argmax rescue
__global__ __launch_bounds__(256) void k_rescore(
    const float* __restrict__ dist, const float* __restrict__ h,
    const float* __restrict__ rnorm, const float* __restrict__ cb,
    const float* __restrict__ scale, int* __restrict__ ind) {
    int row = blockIdx.x;
    const float* dr = dist + (size_t)row * KK_;
    int tid = threadIdx.x;
    float vbuf[16];
    float lmax = -3.4e38f;
    #pragma unroll
    for (int it = 0; it < 16; ++it) {
        float v = dr[tid + it * 256];
        vbuf[it] = v;
        lmax = fmaxf(lmax, v);
    }
    for (int off = 32; off; off >>= 1) lmax = fmaxf(lmax, __shfl_xor(lmax, off));
    __shared__ float wm4[4];
    __shared__ float bmax;
    __shared__ int cnt;
    __shared__ int cand[32];
    __shared__ u64 best;
    int lane = tid & 63, wv = tid >> 6;
    if (lane == 0) wm4[wv] = lmax;
    if (tid == 0) { cnt = 0; best = 0; }
    __syncthreads();
    if (tid == 0) bmax = fmaxf(fmaxf(wm4[0], wm4[1]), fmaxf(wm4[2], wm4[3]));
    __syncthreads();
    float thr = bmax - 1e-3f;
    #pragma unroll
    for (int it = 0; it < 16; ++it) {
        if (vbuf[it] >= thr) {
            int p = atomicAdd(&cnt, 1);
            if (p < 32) cand[p] = tid + it * 256;
        }
    }
    __syncthreads();
    int nc = min(cnt, 32);
    float hr = rnorm[row];
    const float* hp = h + (size_t)row * DD_;
    for (int c = wv; c < nc; c += 4) {
        int col = cand[c];
        const float* cp = cb + (size_t)col * DD_;
        float dot = 0.f;
        #pragma unroll
        for (int j = 0; j < 8; ++j) dot = fmaf(hp[lane + j * 64], cp[lane + j * 64], dot);
        for (int off = 32; off; off >>= 1) dot += __shfl_xor(dot, off);
        if (lane == 0) atomicMax(&best, packKey(dot * hr * scale[col], col));
    }
    __syncthreads();
    if (tid == 0) ind[row] = (int)(~(u32)(best & 0xFFFFFFFFull));
}

// ---------------- fp32 GEMM (kept only for the 6000x40 output) ----------------
__global__ __launch_bounds__(256) void gemm_nn(
    const float* __restrict__ A, const float* __restrict__ B,
    const float* __restrict__ bias, float* __restrict__ C,
    int M, int Ncols, int Kdim) {
    __shared__ float As[16][68];
    __shared__ float Bs[16][68];
    int tid = threadIdx.x;
    int tx = tid & 15, ty = tid >> 4;
    int m0 = blockIdx.y * 64, n0 = blockIdx.x * 64;
    float cv[4][4] = {};
    int ar = tid >> 2;
    int ak = (tid & 3) << 2;
    int am = m0 + ar;
    const float* Arow = (am < M) ? (A + (size_t)am * Kdim) : nullptr;
    int bk = tid >> 4;
    int bn = (tid & 15) << 2;
    for (int k0 = 0; k0 < Kdim; k0 += 16) {
        float4 av = make_float4(0.f, 0.f, 0.f, 0.f);
        if (Arow) av = *(const float4*)(Arow + k0 + ak);
        As[ak + 0][ar] = av.x; As[ak + 1][ar] = av.y;
        As[ak + 2][ar] = av.z; As[ak + 3][ar] = av.w;
        float4 bv = make_float4(0.f, 0.f, 0.f, 0.f);
        if (n0 + bn < Ncols)
            bv = *(const float4*)(B + (size_t)(k0 + bk) * Ncols + n0 + bn);
        Bs[bk][bn + 0] = bv.x; Bs[bk][bn + 1] = bv.y;
        Bs[bk][bn + 2] = bv.z; Bs[bk][bn + 3] = bv.w;
        __syncthreads();
        #pragma unroll
        for (int kk = 0; kk < 16; ++kk) {
            float4 a4 = *(const float4*)&As[kk][ty << 2];
            float4 b4 = *(const float4*)&Bs[kk][tx << 2];
            float ax[4] = {a4.x, a4.y, a4.z, a4.w};
            float bx[4] = {b4.x, b4.y, b4.z, b4.w};
            #pragma unroll
            for (int i = 0; i < 4; ++i)
                #pragma unroll
                for (int j = 0; j < 4; ++j)
                    cv[i][j] = fmaf(ax[i], bx[j], cv[i][j]);
        }
        __syncthreads();
    }
    #pragma unroll
    for (int i = 0; i < 4; ++i) {
        int m = m0 + (ty << 2) + i;
        if (m >= M) continue;
        #pragma unroll
        for (int j = 0; j < 4; ++j) {
            int n = n0 + (tx << 2) + j;
            if (n >= Ncols) continue;
            C[(size_t)m * Ncols + n] = cv[i][j] + bias[n];
        }
    }
}

// ---------------- commit loss: sum (q - h)^2 ----------------
__global__ __launch_bounds__(256) void k_losses(
    const float* __restrict__ h, const float* __restrict__ cb,
    const float* __restrict__ scale, const int* __restrict__ ind,
    float* __restrict__ gacc) {
    float s1 = 0.f;
    for (int idx = blockIdx.x * 256 + threadIdx.x; idx < NN_ * DD_; idx += gridDim.x * 256) {
        int m = idx >> 9, d = idx & 511;
        int r = ind[m];
        float q = cb[(size_t)r * DD_ + d] * scale[r];
        float dq = q - h[idx];
        s1 = fmaf(dq, dq, s1);
    }
    for (int off = 32; off; off >>= 1) s1 += __shfl_xor(s1, off);
    __shared__ float w1[4];
    int lane = threadIdx.x & 63, wv = threadIdx.x >> 6;
    if (lane == 0) w1[wv] = s1;
    __syncthreads();
    if (threadIdx.x == 0) atomicAdd(&gacc[2], w1[0] + w1[1] + w1[2] + w1[3]);
}

// ---------------- edge multiplicity hash (for sum m^2 only) ----------------
__global__ void k_hash(const int* __restrict__ src, const int* __restrict__ dst,
                       int* __restrict__ hkey, int* __restrict__ hcnt) {
    int e = blockIdx.x * 256 + threadIdx.x;
    if (e >= EE_) return;
    int key = dst[e] * NN_ + src[e];
    u32 h = ((u32)key * 2654435761u) & HMASK;
    while (true) {
        int old = atomicCAS(&hkey[h], -1, key);
        if (old == -1 || old == key) { atomicAdd(&hcnt[h], 1); break; }
        h = (h + 1) & HMASK;
    }
}

__global__ __launch_bounds__(256) void k_m2scan(const int* __restrict__ hcnt, float* __restrict__ gacc) {
    float s = 0.f;
    for (int i = blockIdx.x * 256 + threadIdx.x; i < HSZ; i += gridDim.x * 256) {
        float c = (float)hcnt[i];
        s = fmaf(c, c, s);
    }
    for (int off = 32; off; off >>= 1) s += __shfl_xor(s, off);
    __shared__ float w1[4];
    int lane = threadIdx.x & 63, wv = threadIdx.x >> 6;
    if (lane == 0) w1[wv] = s;
    __syncthreads();
    if (threadIdx.x == 0) atomicAdd(&gacc[4], w1[0] + w1[1] + w1[2] + w1[3]);
}

// ---------------- final loss assembly ----------------
__global__ void k_final(const float* __restrict__ gacc, const u32* __restrict__ minKey,
                        const u32* __restrict__ maxKey, float* __restrict__ lossOut) {
    if (threadIdx.x != 0 || blockIdx.x != 0) return;
    double Rsum = gacc[0], Rsq = gacc[1], commitS = gacc[2], recS = gacc[3];
    double m2 = gacc[4], mr = gacc[5], ms = (double)EE_;
    double mn = (double)dkey(*minKey);
    double mx = (double)dkey(*maxKey);
    double den = mx - mn;
    double NN2 = (double)NN_ * (double)NN_;
    double sum_aq2 = (Rsq - 2.0 * mn * Rsum + NN2 * mn * mn) / (den * den);
    double sum_maq = (mr - mn * ms) / den;
    double total = sum_aq2 + m2 - 2.0 * sum_maq;
    double edge = sqrt(total / NN2);
    double commit = 0.25 * commitS / ((double)NN_ * (double)DD_);
    double rec = recS / ((double)NN_ * (double)DD_);
    *lossOut = (float)(rec + edge + commit);
}

extern "C" void kernel_launch(void* const* d_in, const int* in_sizes, int n_in,
                              void* d_out, int out_size, void* d_ws, size_t ws_size,
                              hipStream_t stream) {
    const float* feats = (const float*)d_in[0];
    const float* W1 = (const float*)d_in[1];
    const float* b1 = (const float*)d_in[2];
    const float* W2 = (const float*)d_in[3];
    const float* b2v = (const float*)d_in[4];
    const float* Wd1 = (const float*)d_in[5];
    const float* bd1 = (const float*)d_in[6];
    const float* Wd2 = (const float*)d_in[7];
    const float* bd2 = (const float*)d_in[8];
    const float* Wl = (const float*)d_in[9];
    const float* bl = (const float*)d_in[10];
    const float* cb = (const float*)d_in[11];
    const int* src = (const int*)d_in[12];
    const int* dst = (const int*)d_in[13];

    float* outF = (float*)d_out;
    float* lossOut = outF + (size_t)NN_ * OO_;     // element 240000
    float* distOut = lossOut + 1;                  // element 240001

    char* w = (char*)d_ws;
    size_t off = 0;
    auto alloc = [&](size_t bytes) -> void* {
        void* p = w + off;
        off = (off + bytes + 255) & ~(size_t)255;
        return p;
    };
    // zone0: zero-init
    float* gacc = (float*)alloc(64);
    u32* maxKey = (u32*)alloc(4);
    int* degin = (int*)alloc((size_t)NN_ * 4);
    int* degout = (int*)alloc((size_t)NN_ * 4);
    int* cursor = (int*)alloc((size_t)NN_ * 4);
    int* hcnt = (int*)alloc((size_t)HSZ * 4);
    size_t z0end = off;
    // zone1: 0xFF-init
    int* hkey = (int*)alloc((size_t)HSZ * 4);
    u32* minKey = (u32*)alloc(4);
    size_t z1end = off;
    // uninit scratch
    int* offs = (int*)alloc((size_t)(NN_ + 1) * 4);
    int* esrc = (int*)alloc((size_t)EE_ * 4);
    float* rin = (float*)alloc((size_t)NN_ * 4);
    float* rout = (float*)alloc((size_t)NN_ * 4);
    int* ind = (int*)alloc((size_t)NN_ * 4);
    float* scale = (float*)alloc((size_t)KK_ * 4);
    float* rnorm = (float*)alloc((size_t)NN_ * 4);
    float* h = (float*)alloc((size_t)NN_ * DD_ * 4);       // h, later h2
    float* QE = (float*)alloc((size_t)NN_ * DD_ * 4);
    const size_t NPACK = (size_t)MT_A * 16 * DD_;          // node-sized packed half
    unsigned short* P1 = (unsigned short*)alloc(NPACK * 2 * 2);  // aggp -> qcp -> agg2p
    unsigned short* P2 = (unsigned short*)alloc(NPACK * 2 * 2);  // hnp -> QEp
    unsigned short* enp = (unsigned short*)alloc((size_t)KK_ * DD_ * 2 * 2);
    const size_t WPACK = (size_t)32 * 16 * DD_;            // 512-row packed half
    unsigned short* W1p = (unsigned short*)alloc(WPACK * 2 * 2);
    unsigned short* Wd1p = (unsigned short*)alloc(WPACK * 2 * 2);
    unsigned short* Wd2p = (unsigned short*)alloc(WPACK * 2 * 2);
    unsigned short* W2p = (unsigned short*)alloc(WPACK * 2 * 2);

    unsigned short* aggp_h = P1,  *aggp_l = P1 + NPACK;
    unsigned short* qcp_h  = P1,  *qcp_l  = P1 + NPACK;
    unsigned short* ag2p_h = P1,  *ag2p_l = P1 + NPACK;
    unsigned short* hnp_h  = P2,  *hnp_l  = P2 + NPACK;
    unsigned short* QEp_h  = P2,  *QEp_l  = P2 + NPACK;
    unsigned short* enp_h  = enp, *enp_l  = enp + (size_t)KK_ * DD_;

    hipMemsetAsync(w, 0, z0end, stream);
    hipMemsetAsync(w + z0end, 0xFF, z1end - z0end, stream);

    const int TB = 256;
    k_deg<<<(EE_ + TB - 1) / TB, TB, 0, stream>>>(src, dst, degout, degin);
    k_rsqrtdeg<<<(NN_ + TB - 1) / TB, TB, 0, stream>>>(degout, degin, rout, rin);
    k_scan<<<1, 1024, 0, stream>>>(degin, offs, NN_);
    k_fill<<<(EE_ + TB - 1) / TB, TB, 0, stream>>>(src, dst, offs, cursor, esrc);
    k_wpack<<<dim3(32, 4), TB, 0, stream>>>(W1, W1p, W1p + WPACK);
    k_wpack<<<dim3(32, 4), TB, 0, stream>>>(Wd1, Wd1p, Wd1p + WPACK);
    k_wpack<<<dim3(32, 4), TB, 0, stream>>>(Wd2, Wd2p, Wd2p + WPACK);
    k_wpack<<<dim3(32, 4), TB, 0, stream>>>(W2, W2p, W2p + WPACK);
    k_aggp<<<NN_, TB, 0, stream>>>(feats, esrc, offs, rout, rin, aggp_h, aggp_l);
    gemm_mfma<2><<<dim3(4, NB_N), TB, 0, stream>>>(aggp_h, aggp_l, W1p, W1p + WPACK,
                                                   h, b1, nullptr, 1, NN_, nullptr, nullptr, nullptr);
    k_cbscale<<<NN_, TB, 0, stream>>>(h, rnorm);
    k_cbscale<<<KK_, TB, 0, stream>>>(cb, scale);
    k_pack<<<dim3(MT_A, 4), TB, 0, stream>>>(h, rnorm, nullptr, NN_, hnp_h, hnp_l);
    k_pack<<<dim3(KK_ / 16, 4), TB, 0, stream>>>(cb, scale, nullptr, KK_, enp_h, enp_l);
    gemm_mfma<0><<<dim3(KK_ / 128, NB_N), TB, 0, stream>>>(hnp_h, hnp_l, enp_h, enp_l,
                                                           distOut, nullptr, nullptr, 0, NN_,
                                                           nullptr, nullptr, nullptr);
    k_rescore<<<NN_, TB, 0, stream>>>(distOut, h, rnorm, cb, scale, ind);
    k_pack<<<dim3(MT_A, 4), TB, 0, stream>>>(cb, scale, ind, NN_, qcp_h, qcp_l);
    gemm_mfma<2><<<dim3(4, NB_N), TB, 0, stream>>>(qcp_h, qcp_l, Wd1p, Wd1p + WPACK,
                                                   QE, bd1, nullptr, 0, NN_, nullptr, nullptr, nullptr);
    gemm_mfma<3><<<dim3(4, NB_N), TB, 0, stream>>>(qcp_h, qcp_l, Wd2p, Wd2p + WPACK,
                                                   nullptr, bd2, h, 0, NN_, gacc, nullptr, nullptr);
    k_losses<<<2048, TB, 0, stream>>>(h, cb, scale, ind, gacc);
    k_pack<<<dim3(MT_A, 4), TB, 0, stream>>>(QE, nullptr, nullptr, NN_, QEp_h, QEp_l);
    gemm_mfma<1><<<dim3(NB_N, NB_N), TB, 0, stream>>>(QEp_h, QEp_l, QEp_h, QEp_l,
                                                      nullptr, nullptr, nullptr, 0, NN_,
                                                      gacc, minKey, maxKey);
    k_hash<<<(EE_ + TB - 1) / TB, TB, 0, stream>>>(src, dst, hkey, hcnt);
    k_m2scan<<<512, TB, 0, stream>>>(hcnt, gacc);
    k_aggd<<<NN_, TB, 0, stream>>>(QE, esrc, offs, rout, rin, ag2p_h, ag2p_l, gacc);
    gemm_mfma<2><<<dim3(4, NB_N), TB, 0, stream>>>(ag2p_h, ag2p_l, W2p, W2p + WPACK,
                                                   h, b2v, nullptr, 1, NN_, nullptr, nullptr, nullptr);
    gemm_nn<<<dim3(1, 94), TB, 0, stream>>>(h, Wl, bl, outF, NN_, OO_, DD_);
    k_final<<<1, 64, 0, stream>>>(gacc, minKey, maxKey, lossOut);
}

// Round 5
// 749.536 us; speedup vs baseline: 2.0976x; 1.0173x over previous
//
#include <hip/hip_runtime.h>

typedef unsigned int u32;
typedef unsigned long long u64;

#define NN_ 6000
#define EE_ 192000
#define DD_ 512
#define KK_ 4096
#define OO_ 40
#define HSZ (1 << 19)
#define HMASK (HSZ - 1)
#define MT_A 376   // ceil(6000/16) m-tiles for node-sized packed arrays
#define NB_N 47    // 6016/128 blocks

typedef __bf16 bf16x8 __attribute__((ext_vector_type(8)));
typedef float f32x4 __attribute__((ext_vector_type(4)));

__device__ __forceinline__ u32 okey(float f) {
    u32 u = __float_as_uint(f);
    return (u & 0x80000000u) ? ~u : (u | 0x80000000u);
}
__device__ __forceinline__ float dkey(u32 u) {
    u32 b = (u & 0x80000000u) ? (u ^ 0x80000000u) : ~u;
    return __uint_as_float(b);
}
__device__ __forceinline__ u64 packKey(float v, int col) {
    return ((u64)okey(v) << 32) | (u32)(~(u32)col);
}
__device__ __forceinline__ unsigned short f2bf_rne(float f) {
    u32 x = __float_as_uint(f);
    u32 r = x + 0x7fffu + ((x >> 16) & 1u);
    return (unsigned short)(r >> 16);
}
__device__ __forceinline__ void gld_lds16(void* l, const void* g) {
    __builtin_amdgcn_global_load_lds(
        (const __attribute__((address_space(1))) unsigned int*)g,
        (__attribute__((address_space(3))) unsigned int*)l, 16, 0, 0);
}
// split 8 floats into bf16 hi/lo packed words
__device__ __forceinline__ void split8(const float* vals, uint4& hw, uint4& lw) {
    u32 h[4], l[4];
    #pragma unroll
    for (int j = 0; j < 4; ++j) {
        unsigned short h0 = f2bf_rne(vals[2*j]),   h1 = f2bf_rne(vals[2*j+1]);
        float hf0 = __uint_as_float((u32)h0 << 16), hf1 = __uint_as_float((u32)h1 << 16);
        unsigned short l0 = f2bf_rne(vals[2*j] - hf0), l1 = f2bf_rne(vals[2*j+1] - hf1);
        h[j] = (u32)h0 | ((u32)h1 << 16);
        l[j] = (u32)l0 | ((u32)l1 << 16);
    }
    hw = make_uint4(h[0], h[1], h[2], h[3]);
    lw = make_uint4(l[0], l[1], l[2], l[3]);
}

// ---------------- graph prep ----------------
__global__ void k_deg(const int* __restrict__ src, const int* __restrict__ dst,
                      int* __restrict__ degout, int* __restrict__ degin) {
    int e = blockIdx.x * 256 + threadIdx.x;
    if (e >= EE_) return;
    atomicAdd(&degout[src[e]], 1);
    atomicAdd(&degin[dst[e]], 1);
}

__global__ void k_rsqrtdeg(const int* __restrict__ degout, const int* __restrict__ degin,
                           float* __restrict__ rout, float* __restrict__ rin) {
    int i = blockIdx.x * 256 + threadIdx.x;
    if (i >= NN_) return;
    int doV = degout[i]; if (doV < 1) doV = 1;
    int diV = degin[i];  if (diV < 1) diV = 1;
    rout[i] = rsqrtf((float)doV);
    rin[i]  = rsqrtf((float)diV);
}

__global__ void k_scan(const int* __restrict__ cnt, int* __restrict__ offs, int n) {
    __shared__ int buf[1024];
    __shared__ int carry;
    if (threadIdx.x == 0) { carry = 0; offs[0] = 0; }
    __syncthreads();
    for (int base = 0; base < n; base += 1024) {
        int i = base + threadIdx.x;
        int v = (i < n) ? cnt[i] : 0;
        buf[threadIdx.x] = v;
        __syncthreads();
        for (int off = 1; off < 1024; off <<= 1) {
            int t = (threadIdx.x >= off) ? buf[threadIdx.x - off] : 0;
            __syncthreads();
            buf[threadIdx.x] += t;
            __syncthreads();
        }
        if (i < n) offs[i + 1] = carry + buf[threadIdx.x];
        __syncthreads();
        if (threadIdx.x == 0) carry += buf[1023];
        __syncthreads();
    }
}

__global__ void k_fill(const int* __restrict__ src, const int* __restrict__ dst,
                       const int* __restrict__ offs, int* __restrict__ cursor,
                       int* __restrict__ esrc) {
    int e = blockIdx.x * 256 + threadIdx.x;
    if (e >= EE_) return;
    int d = dst[e];
    int pos = offs[d] + atomicAdd(&cursor[d], 1);
    esrc[pos] = src[e];
}

// write one fp32 row (in LDS) into MFMA-packed hi/lo arrays (threads t<64)
__device__ __forceinline__ void pack_row_from_lds(
    const float* rowbuf, int node, int t,
    unsigned short* __restrict__ dh, unsigned short* __restrict__ dl) {
    int kb = t >> 2, sub = t & 3;
    int lane = sub * 16 + (node & 15);
    uint4 hw, lw;
    split8(rowbuf + t * 8, hw, lw);
    size_t base = (((size_t)(node >> 4) * 16 + kb) * 64 + lane) * 8;
    *(uint4*)(dh + base) = hw;
    *(uint4*)(dl + base) = lw;
}

// aggregation (norm='both') fused with MFMA-pack; 8-way edge unroll for MLP
__global__ __launch_bounds__(256) void k_aggp(
    const float* __restrict__ X, const int* __restrict__ esrc,
    const int* __restrict__ offs, const float* __restrict__ rout,
    const float* __restrict__ rin,
    unsigned short* __restrict__ dh, unsigned short* __restrict__ dl) {
    __shared__ float rowbuf[512];
    int node = blockIdx.x;
    int beg = offs[node], end = offs[node + 1];
    int t = threadIdx.x;
    float a0 = 0.f, a1 = 0.f, b0 = 0.f, b1 = 0.f;
    float c0 = 0.f, c1 = 0.f, d0 = 0.f, d1 = 0.f;
    int e = beg;
    for (; e + 8 <= end; e += 8) {
        int s0 = esrc[e+0], s1 = esrc[e+1], s2 = esrc[e+2], s3 = esrc[e+3];
        int s4 = esrc[e+4], s5 = esrc[e+5], s6 = esrc[e+6], s7 = esrc[e+7];
        float w0 = rout[s0], w1 = rout[s1], w2 = rout[s2], w3 = rout[s3];
        float w4 = rout[s4], w5 = rout[s5], w6 = rout[s6], w7 = rout[s7];
        float2 v0 = ((const float2*)(X + (size_t)s0 * DD_))[t];
        float2 v1 = ((const float2*)(X + (size_t)s1 * DD_))[t];
        float2 v2 = ((const float2*)(X + (size_t)s2 * DD_))[t];
        float2 v3 = ((const float2*)(X + (size_t)s3 * DD_))[t];
        float2 v4 = ((const float2*)(X + (size_t)s4 * DD_))[t];
        float2 v5 = ((const float2*)(X + (size_t)s5 * DD_))[t];
        float2 v6 = ((const float2*)(X + (size_t)s6 * DD_))[t];
        float2 v7 = ((const float2*)(X + (size_t)s7 * DD_))[t];
        a0 = fmaf(w0, v0.x, a0); a1 = fmaf(w0, v0.y, a1);
        b0 = fmaf(w1, v1.x, b0); b1 = fmaf(w1, v1.y, b1);
        c0 = fmaf(w2, v2.x, c0); c1 = fmaf(w2, v2.y, c1);
        d0 = fmaf(w3, v3.x, d0); d1 = fmaf(w3, v3.y, d1);
        a0 = fmaf(w4, v4.x, a0); a1 = fmaf(w4, v4.y, a1);
        b0 = fmaf(w5, v5.x, b0); b1 = fmaf(w5, v5.y, b1);
        c0 = fmaf(w6, v6.x, c0); c1 = fmaf(w6, v6.y, c1);
        d0 = fmaf(w7, v7.x, d0); d1 = fmaf(w7, v7.y, d1);
    }
    for (; e < end; ++e) {
        int s = esrc[e];
        float w = rout[s];
        float2 v = ((const float2*)(X + (size_t)s * DD_))[t];
        a0 = fmaf(w, v.x, a0); a1 = fmaf(w, v.y, a1);
    }
    float ri = rin[node];
    rowbuf[2 * t] = (a0 + b0 + c0 + d0) * ri;
    rowbuf[2 * t + 1] = (a1 + b1 + c1 + d1) * ri;
    __syncthreads();
    if (t < 64) pack_row_from_lds(rowbuf, node, t, dh, dl);
}

// aggregation + pack + unweighted-sum dot with QE row (edge-loss mr term)
__global__ __launch_bounds__(256) void k_aggd(
    const float* __restrict__ QE, const int* __restrict__ esrc,
    const int* __restrict__ offs, const float* __restrict__ rout,
    const float* __restrict__ rin,
    unsigned short* __restrict__ dh, unsigned short* __restrict__ dl,
    float* __restrict__ gacc) {
    __shared__ float rowbuf[512];
    __shared__ float wred[4];
    int node = blockIdx.x;
    int beg = offs[node], end = offs[node + 1];
    int t = threadIdx.x;
    float a0 = 0.f, a1 = 0.f, b0 = 0.f, b1 = 0.f;
    float c0 = 0.f, c1 = 0.f, d0 = 0.f, d1 = 0.f;
    float ua0 = 0.f, ua1 = 0.f, ub0 = 0.f, ub1 = 0.f;
    int e = beg;
    for (; e + 8 <= end; e += 8) {
        int s0 = esrc[e+0], s1 = esrc[e+1], s2 = esrc[e+2], s3 = esrc[e+3];
        int s4 = esrc[e+4], s5 = esrc[e+5], s6 = esrc[e+6], s7 = esrc[e+7];
        float w0 = rout[s0], w1 = rout[s1], w2 = rout[s2], w3 = rout[s3];
        float w4 = rout[s4], w5 = rout[s5], w6 = rout[s6], w7 = rout[s7];
        float2 v0 = ((const float2*)(QE + (size_t)s0 * DD_))[t];
        float2 v1 = ((const float2*)(QE + (size_t)s1 * DD_))[t];
        float2 v2 = ((const float2*)(QE + (size_t)s2 * DD_))[t];
        float2 v3 = ((const float2*)(QE + (size_t)s3 * DD_))[t];
        float2 v4 = ((const float2*)(QE + (size_t)s4 * DD_))[t];
        float2 v5 = ((const float2*)(QE + (size_t)s5 * DD_))[t];
        float2 v6 = ((const float2*)(QE + (size_t)s6 * DD_))[t];
        float2 v7 = ((const float2*)(QE + (size_t)s7 * DD_))[t];
        a0 = fmaf(w0, v0.x, a0); a1 = fmaf(w0, v0.y, a1);
        b0 = fmaf(w1, v1.x, b0); b1 = fmaf(w1, v1.y, b1);
        c0 = fmaf(w2, v2.x, c0); c1 = fmaf(w2, v2.y, c1);
        d0 = fmaf(w3, v3.x, d0); d1 = fmaf(w3, v3.y, d1);
        a0 = fmaf(w4, v4.x, a0); a1 = fmaf(w4, v4.y, a1);
        b0 = fmaf(w5, v5.x, b0); b1 = fmaf(w5, v5.y, b1);
        c0 = fmaf(w6, v6.x, c0); c1 = fmaf(w6, v6.y, c1);
        d0 = fmaf(w7, v7.x, d0); d1 = fmaf(w7, v7.y, d1);
        ua0 += v0.x + v2.x + v4.x + v6.x;
        ua1 += v0.y + v2.y + v4.y + v6.y;
        ub0 += v1.x + v3.x + v5.x + v7.x;
        ub1 += v1.y + v3.y + v5.y + v7.y;
    }
    for (; e < end; ++e) {
        int s = esrc[e];
        float w = rout[s];
        float2 v = ((const float2*)(QE + (size_t)s * DD_))[t];
        a0 = fmaf(w, v.x, a0); a1 = fmaf(w, v.y, a1);
        ua0 += v.x; ua1 += v.y;
    }
    float ri = rin[node];
    rowbuf[2 * t] = (a0 + b0 + c0 + d0) * ri;
    rowbuf[2 * t + 1] = (a1 + b1 + c1 + d1) * ri;
    float2 q = ((const float2*)(QE + (size_t)node * DD_))[t];
    float c = q.x * (ua0 + ub0) + q.y * (ua1 + ub1);
    for (int off = 32; off; off >>= 1) c += __shfl_xor(c, off);
    int lane = t & 63, wv = t >> 6;
    if (lane == 0) wred[wv] = c;
    __syncthreads();
    if (t < 64) pack_row_from_lds(rowbuf, node, t, dh, dl);
    if (t == 0) atomicAdd(&gacc[5], wred[0] + wred[1] + wred[2] + wred[3]);
}

// per-row scale: scale[r] = 1/sqrt(sum row^2 + eps)
__global__ __launch_bounds__(256) void k_cbscale(const float* __restrict__ cb, float* __restrict__ scale) {
    int row = blockIdx.x;
    float2 v = ((const float2*)(cb + (size_t)row * DD_))[threadIdx.x];
    float s = v.x * v.x + v.y * v.y;
    for (int off = 32; off; off >>= 1) s += __shfl_xor(s, off);
    __shared__ float wsum[4];
    int lane = threadIdx.x & 63, wv = threadIdx.x >> 6;
    if (lane == 0) wsum[wv] = s;
    __syncthreads();
    if (threadIdx.x == 0) scale[row] = 1.0f / sqrtf(wsum[0] + wsum[1] + wsum[2] + wsum[3] + 1e-12f);
}

// pack fp32 rows (opt gather + row-scale) into MFMA fragment order, bf16 hi/lo
__global__ __launch_bounds__(256) void k_pack(
    const float* __restrict__ src, const float* __restrict__ rowscale,
    const int* __restrict__ gidx, int nrows,
    unsigned short* __restrict__ dh, unsigned short* __restrict__ dl) {
    int u = threadIdx.x >> 6, lane = threadIdx.x & 63;
    int mt = blockIdx.x, kb = blockIdx.y * 4 + u;
    int gr = mt * 16 + (lane & 15);
    int k = kb * 32 + (lane >> 4) * 8;
    float vals[8] = {0.f,0.f,0.f,0.f,0.f,0.f,0.f,0.f};
    if (gr < nrows) {
        int row = gidx ? gidx[gr] : gr;
        float sc = rowscale ? rowscale[row] : 1.0f;
        const float4* p = (const float4*)(src + (size_t)row * DD_ + k);
        float4 a = p[0], b = p[1];
        vals[0]=a.x*sc; vals[1]=a.y*sc; vals[2]=a.z*sc; vals[3]=a.w*sc;
        vals[4]=b.x*sc; vals[5]=b.y*sc; vals[6]=b.z*sc; vals[7]=b.w*sc;
    }
    uint4 hw, lw;
    split8(vals, hw, lw);
    size_t base = (((size_t)mt * 16 + kb) * 64 + lane) * 8;
    *(uint4*)(dh + base) = hw;
    *(uint4*)(dl + base) = lw;
}

// transpose-pack a [512,512] weight: Bp rows = output cols
__global__ __launch_bounds__(256) void k_wpack(
    const float* __restrict__ W,
    unsigned short* __restrict__ dh, unsigned short* __restrict__ dl) {
    int u = threadIdx.x >> 6, lane = threadIdx.x & 63;
    int mt = blockIdx.x, kb = blockIdx.y * 4 + u;
    int n = mt * 16 + (lane & 15);
    int k = kb * 32 + (lane >> 4) * 8;
    float vals[8];
    #pragma unroll
    for (int j = 0; j < 8; ++j) vals[j] = W[(size_t)(k + j) * DD_ + n];
    uint4 hw, lw;
    split8(vals, hw, lw);
    size_t base = (((size_t)mt * 16 + kb) * 64 + lane) * 8;
    *(uint4*)(dh + base) = hw;
    *(uint4*)(dl + base) = lw;
}

// ---------------- MFMA GEMM, C = A . B^T via split-bf16 (hi/lo, 3 mfma) ----------
// MODE 0: dist — store C fp32 to Cout (stride KK_)
// MODE 1: rpass — upper-tri block grid, reduce sum/sumsq/min/max of symmetric C
// MODE 2: dense — store C+bias (opt relu) to Cout (stride DD_), rows < Mrows
// MODE 3: loss — accumulate sum((Ref - (C+bias))^2) into gacc[3]
template<int MODE>
__global__ __launch_bounds__(256) void gemm_mfma(
    const unsigned short* __restrict__ Ah, const unsigned short* __restrict__ Al,
    const unsigned short* __restrict__ Bh, const unsigned short* __restrict__ Bl,
    float* __restrict__ Cout, const float* __restrict__ bias,
    const float* __restrict__ Ref, int relu, int Mrows,
    float* __restrict__ gacc, u32* __restrict__ minKey, u32* __restrict__ maxKey) {
    if (MODE == 1 && blockIdx.x < blockIdx.y) return;  // bj >= bi only
    __shared__ char lds[32768];  // Ah|Al|Bh|Bl tiles, 8 KB each
    int tid = threadIdx.x;
    int wave = tid >> 6, lane = tid & 63;
    int gmtA = blockIdx.y * 8, gmtB = blockIdx.x * 8;
    const unsigned short* garr; int gmt0;
    if (wave == 0)      { garr = Ah; gmt0 = gmtA; }
    else if (wave == 1) { garr = Al; gmt0 = gmtA; }
    else if (wave == 2) { garr = Bh; gmt0 = gmtB; }
    else                { garr = Bl; gmt0 = gmtB; }
    char* ldst = lds + wave * 8192;
    f32x4 acc[4][4];
    #pragma unroll
    for (int i = 0; i < 4; ++i)
        #pragma unroll
        for (int j = 0; j < 4; ++j) acc[i][j] = (f32x4){0.f, 0.f, 0.f, 0.f};
    int wm = wave >> 1, wn = wave & 1;
    for (int kb = 0; kb < 16; ++kb) {
        #pragma unroll
        for (int t = 0; t < 8; ++t) {
            const char* g = (const char*)garr + (((size_t)(gmt0 + t) * 16 + kb) * 1024) + lane * 16;
            gld_lds16(ldst + t * 1024 + lane * 16, g);
        }
        __syncthreads();
        bf16x8 a_h[4], a_l[4], b_h[4], b_l[4];
        #pragma unroll
        for (int i = 0; i < 4; ++i) {
            int at = wm * 4 + i, bt = wn * 4 + i;
            a_h[i] = *(const bf16x8*)(lds + 0     + at * 1024 + lane * 16);
            a_l[i] = *(const bf16x8*)(lds + 8192  + at * 1024 + lane * 16);
            b_h[i] = *(const bf16x8*)(lds + 16384 + bt * 1024 + lane * 16);
            b_l[i] = *(const bf16x8*)(lds + 24576 + bt * 1024 + lane * 16);
        }
        #pragma unroll
        for (int i = 0; i < 4; ++i)
            #pragma unroll
            for (int j = 0; j < 4; ++j) {
                acc[i][j] = __builtin_amdgcn_mfma_f32_16x16x32_bf16(a_h[i], b_h[j], acc[i][j], 0, 0, 0);
                acc[i][j] = __builtin_amdgcn_mfma_f32_16x16x32_bf16(a_h[i], b_l[j], acc[i][j], 0, 0, 0);
                acc[i][j] = __builtin_amdgcn_mfma_f32_16x16x32_bf16(a_l[i], b_h[j], acc[i][j], 0, 0, 0);
            }
        __syncthreads();
    }
    // C/D layout: col = lane&15, row = (lane>>4)*4 + reg
    int m_base = blockIdx.y * 128 + wm * 64;
    int n_base = blockIdx.x * 128 + wn * 64;
    int rq = lane >> 4, cc = lane & 15;
    if (MODE == 0) {
        #pragma unroll
        for (int i = 0; i < 4; ++i) {
            int m = m_base + i * 16 + rq * 4;
            #pragma unroll
            for (int j = 0; j < 4; ++j) {
                int n = n_base + j * 16 + cc;
                #pragma unroll
                for (int r = 0; r < 4; ++r) {
                    if (m + r < NN_) Cout[(size_t)(m + r) * KK_ + n] = acc[i][j][r];
                }
            }
        }
    } else if (MODE == 2) {
        #pragma unroll
        for (int i = 0; i < 4; ++i) {
            int m = m_base + i * 16 + rq * 4;
            #pragma unroll
            for (int j = 0; j < 4; ++j) {
                int n = n_base + j * 16 + cc;
                float bv = bias[n];
                #pragma unroll
                for (int r = 0; r < 4; ++r) {
                    if (m + r < Mrows) {
                        float v = acc[i][j][r] + bv;
                        if (relu) v = fmaxf(v, 0.f);
                        Cout[(size_t)(m + r) * DD_ + n] = v;
                    }
                }
            }
        }
    } else if (MODE == 3) {
        float s = 0.f;
        #pragma unroll
        for (int i = 0; i < 4; ++i) {
            int m = m_base + i * 16 + rq * 4;
            #pragma unroll
            for (int j = 0; j < 4; ++j) {
                int n = n_base + j * 16 + cc;
                float bv = bias[n];
                #pragma unroll
                for (int r = 0; r < 4; ++r) {
                    if (m + r < Mrows) {
                        float d = Ref[(size_t)(m + r) * DD_ + n] - (acc[i][j][r] + bv);
                        s = fmaf(d, d, s);
                    }
                }
            }
        }
        float* red = (float*)lds;
        red[tid] = s; __syncthreads();
        for (int st = 128; st; st >>= 1) { if (tid < st) red[tid] += red[tid + st]; __syncthreads(); }
        if (tid == 0) atomicAdd(&gacc[3], red[0]);
    } else {
        float tsum = 0.f, tsq = 0.f, tmin = 3.4e38f, tmax = -3.4e38f;
        #pragma unroll
        for (int i = 0; i < 4; ++i) {
            #pragma unroll
            for (int j = 0; j < 4; ++j) {
                #pragma unroll
                for (int r = 0; r < 4; ++r) {
                    int m = m_base + i * 16 + rq * 4 + r;
                    int n = n_base + j * 16 + cc;
                    if (m < NN_ && n < NN_ && n >= m) {
                        float v = acc[i][j][r];
                        float w = (n > m) ? 2.f : 1.f;
                        tsum += w * v;
                        tsq  += w * v * v;
                        tmin = fminf(tmin, v);
                        tmax = fmaxf(tmax, v);
                    }
                }
            }
        }
        float* red = (float*)lds;
        red[tid] = tsum; __syncthreads();
        for (int s = 128; s; s >>= 1) { if (tid < s) red[tid] += red[tid + s]; __syncthreads(); }
        if (tid == 0) atomicAdd(&gacc[0], red[0]);
        __syncthreads();
        red[tid] = tsq; __syncthreads();
        for (int s = 128; s; s >>= 1) { if (tid < s) red[tid] += red[tid + s]; __syncthreads(); }
        if (tid == 0) atomicAdd(&gacc[1], red[0]);
        __syncthreads();
        red[tid] = tmin; __syncthreads();
        for (int s = 128; s; s >>= 1) { if (tid < s) red[tid] = fminf(red[tid], red[tid + s]); __syncthreads(); }
        if (tid == 0) atomicMin(minKey, okey(red[0]));
        __syncthreads();
        red[tid] = tmax; __syncthreads();
        for (int s = 128; s; s >>= 1) { if (tid < s) red[tid] = fmaxf(red[tid], red[tid + s]); __syncthreads(); }
        if (tid == 0) atomicMax(maxKey, okey(red[0]));
    }
}

// exact-fp32 argmax rescue (float4 dist reads)
__global__ __launch_bounds__(256) void k_rescore(
    const float* __restrict__ dist, const float* __restrict__ h,
    const float* __restrict__ rnorm, const float* __restrict__ cb,
    const float* __restrict__ scale, int* __restrict__ ind) {
    int row = blockIdx.x;
    const float4* dr4 = (const float4*)(dist + (size_t)row * KK_);
    int tid = threadIdx.x;
    float4 vbuf[4];
    float lmax = -3.4e38f;
    #pragma unroll
    for (int it = 0; it < 4; ++it) {
        float4 v = dr4[tid + it * 256];
        vbuf[it] = v;
        lmax = fmaxf(fmaxf(fmaxf(v.x, v.y), fmaxf(v.z, v.w)), lmax);
    }
    for (int off = 32; off; off >>= 1) lmax = fmaxf(lmax, __shfl_xor(lmax, off));
    __shared__ float wm4[4];
    __shared__ float bmax;
    __shared__ int cnt;
    __shared__ int cand[32];
    __shared__ u64 best;
    int lane = tid & 63, wv = tid >> 6;
    if (lane == 0) wm4[wv] = lmax;
    if (tid == 0) { cnt = 0; best = 0; }
    __syncthreads();
    if (tid == 0) bmax = fmaxf(fmaxf(wm4[0], wm4[1]), fmaxf(wm4[2], wm4[3]));
    __syncthreads();
    float thr = bmax - 1e-3f;
    #pragma unroll
    for (int it = 0; it < 4; ++it) {
        float4 v = vbuf[it];
        int cbase = (tid + it * 256) * 4;
        if (v.x >= thr) { int p = atomicAdd(&cnt, 1); if (p < 32) cand[p] = cbase + 0; }
        if (v.y >= thr) { int p = atomicAdd(&cnt, 1); if (p < 32) cand[p] = cbase + 1; }
        if (v.z >= thr) { int p = atomicAdd(&cnt, 1); if (p < 32) cand[p] = cbase + 2; }
        if (v.w >= thr) { int p = atomicAdd(&cnt, 1); if (p < 32) cand[p] = cbase + 3; }
    }
    __syncthreads();
    int nc = min(cnt, 32);
    float hr = rnorm[row];
    const float* hp = h + (size_t)row * DD_;
    for (int c = wv; c < nc; c += 4) {
        int col = cand[c];
        const float* cp = cb + (size_t)col * DD_;
        float dot = 0.f;
        #pragma unroll
        for (int j = 0; j < 8; ++j) dot = fmaf(hp[lane + j * 64], cp[lane + j * 64], dot);
        for (int off = 32; off; off >>= 1) dot += __shfl_xor(dot, off);
        if (lane == 0) atomicMax(&best, packKey(dot * hr * scale[col], col));
    }
    __syncthreads();
    if (tid == 0) ind[row] = (int)(~(u32)(best & 0xFFFFFFFFull));
}

// ---------------- fp32 GEMM (kept only for the 6000x40 output) ----------------
__global__ __launch_bounds__(256) void gemm_nn(
    const float* __restrict__ A, const float* __restrict__ B,
    const float* __restrict__ bias, float* __restrict__ C,
    int M, int Ncols, int Kdim) {
    __shared__ float As[16][68];
    __shared__ float Bs[16][68];
    int tid = threadIdx.x;
    int tx = tid & 15, ty = tid >> 4;
    int m0 = blockIdx.y * 64, n0 = blockIdx.x * 64;
    float cv[4][4] = {};
    int ar = tid >> 2;
    int ak = (tid & 3) << 2;
    int am = m0 + ar;
    const float* Arow = (am < M) ? (A + (size_t)am * Kdim) : nullptr;
    int bk = tid >> 4;
    int bn = (tid & 15) << 2;
    for (int k0 = 0; k0 < Kdim; k0 += 16) {
        float4 av = make_float4(0.f, 0.f, 0.f, 0.f);
        if (Arow) av = *(const float4*)(Arow + k0 + ak);
        As[ak + 0][ar] = av.x; As[ak + 1][ar] = av.y;
        As[ak + 2][ar] = av.z; As[ak + 3][ar] = av.w;
        float4 bv = make_float4(0.f, 0.f, 0.f, 0.f);
        if (n0 + bn < Ncols)
            bv = *(const float4*)(B + (size_t)(k0 + bk) * Ncols + n0 + bn);
        Bs[bk][bn + 0] = bv.x; Bs[bk][bn + 1] = bv.y;
        Bs[bk][bn + 2] = bv.z; Bs[bk][bn + 3] = bv.w;
        __syncthreads();
        #pragma unroll
        for (int kk = 0; kk < 16; ++kk) {
            float4 a4 = *(const float4*)&As[kk][ty << 2];
            float4 b4 = *(const float4*)&Bs[kk][tx << 2];
            float ax[4] = {a4.x, a4.y, a4.z, a4.w};
            float bx[4] = {b4.x, b4.y, b4.z, b4.w};
            #pragma unroll
            for (int i = 0; i < 4; ++i)
                #pragma unroll
                for (int j = 0; j < 4; ++j)
                    cv[i][j] = fmaf(ax[i], bx[j], cv[i][j]);
        }
        __syncthreads();
    }
    #pragma unroll
    for (int i = 0; i < 4; ++i) {
        int m = m0 + (ty << 2) + i;
        if (m >= M) continue;
        #pragma unroll
        for (int j = 0; j < 4; ++j) {
            int n = n0 + (tx << 2) + j;
            if (n >= Ncols) continue;
            C[(size_t)m * Ncols + n] = cv[i][j] + bias[n];
        }
    }
}

// ---------------- commit loss: sum (q - h)^2 ----------------
__global__ __launch_bounds__(256) void k_losses(
    const float* __restrict__ h, const float* __restrict__ cb,
    const float* __restrict__ scale, const int* __restrict__ ind,
    float* __restrict__ gacc) {
    float s1 = 0.f;
    for (int idx = blockIdx.x * 256 + threadIdx.x; idx < NN_ * DD_; idx += gridDim.x * 256) {
        int m = idx >> 9, d = idx & 511;
        int r = ind[m];
        float q = cb[(size_t)r * DD_ + d] * scale[r];
        float dq = q - h[idx];
        s1 = fmaf(dq, dq, s1);
    }
    for (int off = 32; off; off >>= 1) s1 += __shfl_xor(s1, off);
    __shared__ float w1[4];
    int lane = threadIdx.x & 63, wv = threadIdx.x >> 6;
    if (lane == 0) w1[wv] = s1;
    __syncthreads();
    if (threadIdx.x == 0) atomicAdd(&gacc[2], w1[0] + w1[1] + w1[2] + w1[3]);
}

// ---------------- edge multiplicity hash (for sum m^2 only) ----------------
__global__ void k_hash(const int* __restrict__ src, const int* __restrict__ dst,
                       int* __restrict__ hkey, int* __restrict__ hcnt) {
    int e = blockIdx.x * 256 + threadIdx.x;
    if (e >= EE_) return;
    int key = dst[e] * NN_ + src[e];
    u32 h = ((u32)key * 2654435761u) & HMASK;
    while (true) {
        int old = atomicCAS(&hkey[h], -1, key);
        if (old == -1 || old == key) { atomicAdd(&hcnt[h], 1); break; }
        h = (h + 1) & HMASK;
    }
}

__global__ __launch_bounds__(256) void k_m2scan(const int* __restrict__ hcnt, float* __restrict__ gacc) {
    float s = 0.f;
    for (int i = blockIdx.x * 256 + threadIdx.x; i < HSZ; i += gridDim.x * 256) {
        float c = (float)hcnt[i];
        s = fmaf(c, c, s);
    }
    for (int off = 32; off; off >>= 1) s += __shfl_xor(s, off);
    __shared__ float w1[4];
    int lane = threadIdx.x & 63, wv = threadIdx.x >> 6;
    if (lane == 0) w1[wv] = s;
    __syncthreads();
    if (threadIdx.x == 0) atomicAdd(&gacc[4], w1[0] + w1[1] + w1[2] + w1[3]);
}

// ---------------- final loss assembly ----------------
__global__ void k_final(const float* __restrict__ gacc, const u32* __restrict__ minKey,
                        const u32* __restrict__ maxKey, float* __restrict__ lossOut) {
    if (threadIdx.x != 0 || blockIdx.x != 0) return;
    double Rsum = gacc[0], Rsq = gacc[1], commitS = gacc[2], recS = gacc[3];
    double m2 = gacc[4], mr = gacc[5], ms = (double)EE_;
    double mn = (double)dkey(*minKey);
    double mx = (double)dkey(*maxKey);
    double den = mx - mn;
    double NN2 = (double)NN_ * (double)NN_;
    double sum_aq2 = (Rsq - 2.0 * mn * Rsum + NN2 * mn * mn) / (den * den);
    double sum_maq = (mr - mn * ms) / den;
    double total = sum_aq2 + m2 - 2.0 * sum_maq;
    double edge = sqrt(total / NN2);
    double commit = 0.25 * commitS / ((double)NN_ * (double)DD_);
    double rec = recS / ((double)NN_ * (double)DD_);
    *lossOut = (float)(rec + edge + commit);
}

extern "C" void kernel_launch(void* const* d_in, const int* in_sizes, int n_in,
                              void* d_out, int out_size, void* d_ws, size_t ws_size,
                              hipStream_t stream) {
    const float* feats = (const float*)d_in[0];
    const float* W1 = (const float*)d_in[1];
    const float* b1 = (const float*)d_in[2];
    const float* W2 = (const float*)d_in[3];
    const float* b2v = (const float*)d_in[4];
    const float* Wd1 = (const float*)d_in[5];
    const float* bd1 = (const float*)d_in[6];
    const float* Wd2 = (const float*)d_in[7];
    const float* bd2 = (const float*)d_in[8];
    const float* Wl = (const float*)d_in[9];
    const float* bl = (const float*)d_in[10];
    const float* cb = (const float*)d_in[11];
    const int* src = (const int*)d_in[12];
    const int* dst = (const int*)d_in[13];

    float* outF = (float*)d_out;
    float* lossOut = outF + (size_t)NN_ * OO_;     // element 240000
    float* distOut = lossOut + 1;                  // element 240001

    char* w = (char*)d_ws;
    size_t off = 0;
    auto alloc = [&](size_t bytes) -> void* {
        void* p = w + off;
        off = (off + bytes + 255) & ~(size_t)255;
        return p;
    };
    // zone0: zero-init
    float* gacc = (float*)alloc(64);
    u32* maxKey = (u32*)alloc(4);
    int* degin = (int*)alloc((size_t)NN_ * 4);
    int* degout = (int*)alloc((size_t)NN_ * 4);
    int* cursor = (int*)alloc((size_t)NN_ * 4);
    int* hcnt = (int*)alloc((size_t)HSZ * 4);
    size_t z0end = off;
    // zone1: 0xFF-init
    int* hkey = (int*)alloc((size_t)HSZ * 4);
    u32* minKey = (u32*)alloc(4);
    size_t z1end = off;
    // uninit scratch
    int* offs = (int*)alloc((size_t)(NN_ + 1) * 4);
    int* esrc = (int*)alloc((size_t)EE_ * 4);
    float* rin = (float*)alloc((size_t)NN_ * 4);
    float* rout = (float*)alloc((size_t)NN_ * 4);
    int* ind = (int*)alloc((size_t)NN_ * 4);
    float* scale = (float*)alloc((size_t)KK_ * 4);
    float* rnorm = (float*)alloc((size_t)NN_ * 4);
    float* h = (float*)alloc((size_t)NN_ * DD_ * 4);       // h, later h2
    float* QE = (float*)alloc((size_t)NN_ * DD_ * 4);
    const size_t NPACK = (size_t)MT_A * 16 * DD_;          // node-sized packed half
    unsigned short* P1 = (unsigned short*)alloc(NPACK * 2 * 2);  // aggp -> qcp -> agg2p
    unsigned short* P2 = (unsigned short*)alloc(NPACK * 2 * 2);  // hnp -> QEp
    unsigned short* enp = (unsigned short*)alloc((size_t)KK_ * DD_ * 2 * 2);
    const size_t WPACK = (size_t)32 * 16 * DD_;            // 512-row packed half
    unsigned short* W1p = (unsigned short*)alloc(WPACK * 2 * 2);
    unsigned short* Wd1p = (unsigned short*)alloc(WPACK * 2 * 2);
    unsigned short* Wd2p = (unsigned short*)alloc(WPACK * 2 * 2);
    unsigned short* W2p = (unsigned short*)alloc(WPACK * 2 * 2);

    unsigned short* aggp_h = P1,  *aggp_l = P1 + NPACK;
    unsigned short* qcp_h  = P1,  *qcp_l  = P1 + NPACK;
    unsigned short* ag2p_h = P1,  *ag2p_l = P1 + NPACK;
    unsigned short* hnp_h  = P2,  *hnp_l  = P2 + NPACK;
    unsigned short* QEp_h  = P2,  *QEp_l  = P2 + NPACK;
    unsigned short* enp_h  = enp, *enp_l  = enp + (size_t)KK_ * DD_;

    hipMemsetAsync(w, 0, z0end, stream);
    hipMemsetAsync(w + z0end, 0xFF, z1end - z0end, stream);

    const int TB = 256;
    k_deg<<<(EE_ + TB - 1) / TB, TB, 0, stream>>>(src, dst, degout, degin);
    k_rsqrtdeg<<<(NN_ + TB - 1) / TB, TB, 0, stream>>>(degout, degin, rout, rin);
    k_scan<<<1, 1024, 0, stream>>>(degin, offs, NN_);
    k_fill<<<(EE_ + TB - 1) / TB, TB, 0, stream>>>(src, dst, offs, cursor, esrc);
    k_wpack<<<dim3(32, 4), TB, 0, stream>>>(W1, W1p, W1p + WPACK);
    k_wpack<<<dim3(32, 4), TB, 0, stream>>>(Wd1, Wd1p, Wd1p + WPACK);
    k_wpack<<<dim3(32, 4), TB, 0, stream>>>(Wd2, Wd2p, Wd2p + WPACK);
    k_wpack<<<dim3(32, 4), TB, 0, stream>>>(W2, W2p, W2p + WPACK);
    k_aggp<<<NN_, TB, 0, stream>>>(feats, esrc, offs, rout, rin, aggp_h, aggp_l);
    gemm_mfma<2><<<dim3(4, NB_N), TB, 0, stream>>>(aggp_h, aggp_l, W1p, W1p + WPACK,
                                                   h, b1, nullptr, 1, NN_, nullptr, nullptr, nullptr);
    k_cbscale<<<NN_, TB, 0, stream>>>(h, rnorm);
    k_cbscale<<<KK_, TB, 0, stream>>>(cb, scale);
    k_pack<<<dim3(MT_A, 4), TB, 0, stream>>>(h, rnorm, nullptr, NN_, hnp_h, hnp_l);
    k_pack<<<dim3(KK_ / 16, 4), TB, 0, stream>>>(cb, scale, nullptr, KK_, enp_h, enp_l);
    gemm_mfma<0><<<dim3(KK_ / 128, NB_N), TB, 0, stream>>>(hnp_h, hnp_l, enp_h, enp_l,
                                                           distOut, nullptr, nullptr, 0, NN_,
                                                           nullptr, nullptr, nullptr);
    k_rescore<<<NN_, TB, 0, stream>>>(distOut, h, rnorm, cb, scale, ind);
    k_pack<<<dim3(MT_A, 4), TB, 0, stream>>>(cb, scale, ind, NN_, qcp_h, qcp_l);
    gemm_mfma<2><<<dim3(4, NB_N), TB, 0, stream>>>(qcp_h, qcp_l, Wd1p, Wd1p + WPACK,
                                                   QE, bd1, nullptr, 0, NN_, nullptr, nullptr, nullptr);
    gemm_mfma<3><<<dim3(4, NB_N), TB, 0, stream>>>(qcp_h, qcp_l, Wd2p, Wd2p + WPACK,
                                                   nullptr, bd2, h, 0, NN_, gacc, nullptr, nullptr);
    k_losses<<<2048, TB, 0, stream>>>(h, cb, scale, ind, gacc);
    k_pack<<<dim3(MT_A, 4), TB, 0, stream>>>(QE, nullptr, nullptr, NN_, QEp_h, QEp_l);
    gemm_mfma<1><<<dim3(NB_N, NB_N), TB, 0, stream>>>(QEp_h, QEp_l, QEp_h, QEp_l,
                                                      nullptr, nullptr, nullptr, 0, NN_,
                                                      gacc, minKey, maxKey);
    k_hash<<<(EE_ + TB - 1) / TB, TB, 0, stream>>>(src, dst, hkey, hcnt);
    k_m2scan<<<512, TB, 0, stream>>>(hcnt, gacc);
    k_aggd<<<NN_, TB, 0, stream>>>(QE, esrc, offs, rout, rin, ag2p_h, ag2p_l, gacc);
    gemm_mfma<2><<<dim3(4, NB_N), TB, 0, stream>>>(ag2p_h, ag2p_l, W2p, W2p + WPACK,
                                                   h, b2v, nullptr, 1, NN_, nullptr, nullptr, nullptr);
    gemm_nn<<<dim3(1, 94), TB, 0, stream>>>(h, Wl, bl, outF, NN_, OO_, DD_);
    k_final<<<1, 64, 0, stream>>>(gacc, minKey, maxKey, lossOut);
}

// Round 6
// 741.776 us; speedup vs baseline: 2.1195x; 1.0105x over previous
//
#include <hip/hip_runtime.h>

typedef unsigned int u32;
typedef unsigned long long u64;

#define NN_ 6000
#define EE_ 192000
#define DD_ 512
#define KK_ 4096
#define OO_ 40
#define HSZ (1 << 19)
#define HMASK (HSZ - 1)
#define MT_A 376   // ceil(6000/16) m-tiles for node-sized packed arrays
#define NB_N 47    // 6016/128 blocks

typedef __bf16 bf16x8 __attribute__((ext_vector_type(8)));
typedef float f32x4 __attribute__((ext_vector_type(4)));
typedef float f32x2 __attribute__((ext_vector_type(2)));

__device__ __forceinline__ u32 okey(float f) {
    u32 u = __float_as_uint(f);
    return (u & 0x80000000u) ? ~u : (u | 0x80000000u);
}
__device__ __forceinline__ float dkey(u32 u) {
    u32 b = (u & 0x80000000u) ? (u ^ 0x80000000u) : ~u;
    return __uint_as_float(b);
}
__device__ __forceinline__ u64 packKey(float v, int col) {
    return ((u64)okey(v) << 32) | (u32)(~(u32)col);
}
__device__ __forceinline__ unsigned short f2bf_rne(float f) {
    u32 x = __float_as_uint(f);
    u32 r = x + 0x7fffu + ((x >> 16) & 1u);
    return (unsigned short)(r >> 16);
}
__device__ __forceinline__ void gld_lds16(void* l, const void* g) {
    __builtin_amdgcn_global_load_lds(
        (const __attribute__((address_space(1))) unsigned int*)g,
        (__attribute__((address_space(3))) unsigned int*)l, 16, 0, 0);
}
// batched gather: 8 simultaneously-outstanding dwordx2 loads (forces MLP the
// compiler's register-minimizing scheduler otherwise trades away — R5 VGPR=24)
__device__ __forceinline__ void gl8(
    const void* p0, const void* p1, const void* p2, const void* p3,
    const void* p4, const void* p5, const void* p6, const void* p7,
    f32x2& v0, f32x2& v1, f32x2& v2, f32x2& v3,
    f32x2& v4, f32x2& v5, f32x2& v6, f32x2& v7) {
    asm volatile(
        "global_load_dwordx2 %0, %8, off\n\t"
        "global_load_dwordx2 %1, %9, off\n\t"
        "global_load_dwordx2 %2, %10, off\n\t"
        "global_load_dwordx2 %3, %11, off\n\t"
        "global_load_dwordx2 %4, %12, off\n\t"
        "global_load_dwordx2 %5, %13, off\n\t"
        "global_load_dwordx2 %6, %14, off\n\t"
        "global_load_dwordx2 %7, %15, off\n\t"
        "s_waitcnt vmcnt(0)"
        : "=&v"(v0), "=&v"(v1), "=&v"(v2), "=&v"(v3),
          "=&v"(v4), "=&v"(v5), "=&v"(v6), "=&v"(v7)
        : "v"(p0), "v"(p1), "v"(p2), "v"(p3),
          "v"(p4), "v"(p5), "v"(p6), "v"(p7)
        : "memory");
}
// split 8 floats into bf16 hi/lo packed words
__device__ __forceinline__ void split8(const float* vals, uint4& hw, uint4& lw) {
    u32 h[4], l[4];
    #pragma unroll
    for (int j = 0; j < 4; ++j) {
        unsigned short h0 = f2bf_rne(vals[2*j]),   h1 = f2bf_rne(vals[2*j+1]);
        float hf0 = __uint_as_float((u32)h0 << 16), hf1 = __uint_as_float((u32)h1 << 16);
        unsigned short l0 = f2bf_rne(vals[2*j] - hf0), l1 = f2bf_rne(vals[2*j+1] - hf1);
        h[j] = (u32)h0 | ((u32)h1 << 16);
        l[j] = (u32)l0 | ((u32)l1 << 16);
    }
    hw = make_uint4(h[0], h[1], h[2], h[3]);
    lw = make_uint4(l[0], l[1], l[2], l[3]);
}

// ---------------- graph prep ----------------
__global__ void k_deg(const int* __restrict__ src, const int* __restrict__ dst,
                      int* __restrict__ degout, int* __restrict__ degin) {
    int e = blockIdx.x * 256 + threadIdx.x;
    if (e >= EE_) return;
    atomicAdd(&degout[src[e]], 1);
    atomicAdd(&degin[dst[e]], 1);
}

__global__ void k_rsqrtdeg(const int* __restrict__ degout, const int* __restrict__ degin,
                           float* __restrict__ rout, float* __restrict__ rin) {
    int i = blockIdx.x * 256 + threadIdx.x;
    if (i >= NN_) return;
    int doV = degout[i]; if (doV < 1) doV = 1;
    int diV = degin[i];  if (diV < 1) diV = 1;
    rout[i] = rsqrtf((float)doV);
    rin[i]  = rsqrtf((float)diV);
}

__global__ void k_scan(const int* __restrict__ cnt, int* __restrict__ offs, int n) {
    __shared__ int buf[1024];
    __shared__ int carry;
    if (threadIdx.x == 0) { carry = 0; offs[0] = 0; }
    __syncthreads();
    for (int base = 0; base < n; base += 1024) {
        int i = base + threadIdx.x;
        int v = (i < n) ? cnt[i] : 0;
        buf[threadIdx.x] = v;
        __syncthreads();
        for (int off = 1; off < 1024; off <<= 1) {
            int t = (threadIdx.x >= off) ? buf[threadIdx.x - off] : 0;
            __syncthreads();
            buf[threadIdx.x] += t;
            __syncthreads();
        }
        if (i < n) offs[i + 1] = carry + buf[threadIdx.x];
        __syncthreads();
        if (threadIdx.x == 0) carry += buf[1023];
        __syncthreads();
    }
}

__global__ void k_fill(const int* __restrict__ src, const int* __restrict__ dst,
                       const int* __restrict__ offs, int* __restrict__ cursor,
                       int* __restrict__ esrc) {
    int e = blockIdx.x * 256 + threadIdx.x;
    if (e >= EE_) return;
    int d = dst[e];
    int pos = offs[d] + atomicAdd(&cursor[d], 1);
    esrc[pos] = src[e];
}

// write one fp32 row (in LDS) into MFMA-packed hi/lo arrays (threads t<64)
__device__ __forceinline__ void pack_row_from_lds(
    const float* rowbuf, int node, int t,
    unsigned short* __restrict__ dh, unsigned short* __restrict__ dl) {
    int kb = t >> 2, sub = t & 3;
    int lane = sub * 16 + (node & 15);
    uint4 hw, lw;
    split8(rowbuf + t * 8, hw, lw);
    size_t base = (((size_t)(node >> 4) * 16 + kb) * 64 + lane) * 8;
    *(uint4*)(dh + base) = hw;
    *(uint4*)(dl + base) = lw;
}

// aggregation (norm='both') fused with MFMA-pack; asm-batched 8-way gather
__global__ __launch_bounds__(256) void k_aggp(
    const float* __restrict__ X, const int* __restrict__ esrc,
    const int* __restrict__ offs, const float* __restrict__ rout,
    const float* __restrict__ rin,
    unsigned short* __restrict__ dh, unsigned short* __restrict__ dl) {
    __shared__ float rowbuf[512];
    int node = blockIdx.x;
    int beg = offs[node], end = offs[node + 1];
    int t = threadIdx.x;
    float a0 = 0.f, a1 = 0.f, b0 = 0.f, b1 = 0.f;
    float c0 = 0.f, c1 = 0.f, d0 = 0.f, d1 = 0.f;
    int e = beg;
    for (; e + 8 <= end; e += 8) {
        int s0 = esrc[e+0], s1 = esrc[e+1], s2 = esrc[e+2], s3 = esrc[e+3];
        int s4 = esrc[e+4], s5 = esrc[e+5], s6 = esrc[e+6], s7 = esrc[e+7];
        f32x2 v0, v1, v2, v3, v4, v5, v6, v7;
        gl8(X + (size_t)s0 * DD_ + 2 * t, X + (size_t)s1 * DD_ + 2 * t,
            X + (size_t)s2 * DD_ + 2 * t, X + (size_t)s3 * DD_ + 2 * t,
            X + (size_t)s4 * DD_ + 2 * t, X + (size_t)s5 * DD_ + 2 * t,
            X + (size_t)s6 * DD_ + 2 * t, X + (size_t)s7 * DD_ + 2 * t,
            v0, v1, v2, v3, v4, v5, v6, v7);
        float w0 = rout[s0], w1 = rout[s1], w2 = rout[s2], w3 = rout[s3];
        float w4 = rout[s4], w5 = rout[s5], w6 = rout[s6], w7 = rout[s7];
        a0 = fmaf(w0, v0[0], a0); a1 = fmaf(w0, v0[1], a1);
        b0 = fmaf(w1, v1[0], b0); b1 = fmaf(w1, v1[1], b1);
        c0 = fmaf(w2, v2[0], c0); c1 = fmaf(w2, v2[1], c1);
        d0 = fmaf(w3, v3[0], d0); d1 = fmaf(w3, v3[1], d1);
        a0 = fmaf(w4, v4[0], a0); a1 = fmaf(w4, v4[1], a1);
        b0 = fmaf(w5, v5[0], b0); b1 = fmaf(w5, v5[1], b1);
        c0 = fmaf(w6, v6[0], c0); c1 = fmaf(w6, v6[1], c1);
        d0 = fmaf(w7, v7[0], d0); d1 = fmaf(w7, v7[1], d1);
    }
    for (; e < end; ++e) {
        int s = esrc[e];
        float w = rout[s];
        float2 v = ((const float2*)(X + (size_t)s * DD_))[t];
        a0 = fmaf(w, v.x, a0); a1 = fmaf(w, v.y, a1);
    }
    float ri = rin[node];
    rowbuf[2 * t] = (a0 + b0 + c0 + d0) * ri;
    rowbuf[2 * t + 1] = (a1 + b1 + c1 + d1) * ri;
    __syncthreads();
    if (t < 64) pack_row_from_lds(rowbuf, node, t, dh, dl);
}

// aggregation + pack + unweighted-sum dot with QE row (edge-loss mr term)
__global__ __launch_bounds__(256) void k_aggd(
    const float* __restrict__ QE, const int* __restrict__ esrc,
    const int* __restrict__ offs, const float* __restrict__ rout,
    const float* __restrict__ rin,
    unsigned short* __restrict__ dh, unsigned short* __restrict__ dl,
    float* __restrict__ gacc) {
    __shared__ float rowbuf[512];
    __shared__ float wred[4];
    int node = blockIdx.x;
    int beg = offs[node], end = offs[node + 1];
    int t = threadIdx.x;
    float a0 = 0.f, a1 = 0.f, b0 = 0.f, b1 = 0.f;
    float c0 = 0.f, c1 = 0.f, d0 = 0.f, d1 = 0.f;
    float ua0 = 0.f, ua1 = 0.f, ub0 = 0.f, ub1 = 0.f;
    int e = beg;
    for (; e + 8 <= end; e += 8) {
        int s0 = esrc[e+0], s1 = esrc[e+1], s2 = esrc[e+2], s3 = esrc[e+3];
        int s4 = esrc[e+4], s5 = esrc[e+5], s6 = esrc[e+6], s7 = esrc[e+7];
        f32x2 v0, v1, v2, v3, v4, v5, v6, v7;
        gl8(QE + (size_t)s0 * DD_ + 2 * t, QE + (size_t)s1 * DD_ + 2 * t,
            QE + (size_t)s2 * DD_ + 2 * t, QE + (size_t)s3 * DD_ + 2 * t,
            QE + (size_t)s4 * DD_ + 2 * t, QE + (size_t)s5 * DD_ + 2 * t,
            QE + (size_t)s6 * DD_ + 2 * t, QE + (size_t)s7 * DD_ + 2 * t,
            v0, v1, v2, v3, v4, v5, v6, v7);
        float w0 = rout[s0], w1 = rout[s1], w2 = rout[s2], w3 = rout[s3];
        float w4 = rout[s4], w5 = rout[s5], w6 = rout[s6], w7 = rout[s7];
        a0 = fmaf(w0, v0[0], a0); a1 = fmaf(w0, v0[1], a1);
        b0 = fmaf(w1, v1[0], b0); b1 = fmaf(w1, v1[1], b1);
        c0 = fmaf(w2, v2[0], c0); c1 = fmaf(w2, v2[1], c1);
        d0 = fmaf(w3, v3[0], d0); d1 = fmaf(w3, v3[1], d1);
        a0 = fmaf(w4, v4[0], a0); a1 = fmaf(w4, v4[1], a1);
        b0 = fmaf(w5, v5[0], b0); b1 = fmaf(w5, v5[1], b1);
        c0 = fmaf(w6, v6[0], c0); c1 = fmaf(w6, v6[1], c1);
        d0 = fmaf(w7, v7[0], d0); d1 = fmaf(w7, v7[1], d1);
        ua0 += v0[0] + v2[0] + v4[0] + v6[0];
        ua1 += v0[1] + v2[1] + v4[1] + v6[1];
        ub0 += v1[0] + v3[0] + v5[0] + v7[0];
        ub1 += v1[1] + v3[1] + v5[1] + v7[1];
    }
    for (; e < end; ++e) {
        int s = esrc[e];
        float w = rout[s];
        float2 v = ((const float2*)(QE + (size_t)s * DD_))[t];
        a0 = fmaf(w, v.x, a0); a1 = fmaf(w, v.y, a1);
        ua0 += v.x; ua1 += v.y;
    }
    float ri = rin[node];
    rowbuf[2 * t] = (a0 + b0 + c0 + d0) * ri;
    rowbuf[2 * t + 1] = (a1 + b1 + c1 + d1) * ri;
    float2 q = ((const float2*)(QE + (size_t)node * DD_))[t];
    float c = q.x * (ua0 + ub0) + q.y * (ua1 + ub1);
    for (int off = 32; off; off >>= 1) c += __shfl_xor(c, off);
    int lane = t & 63, wv = t >> 6;
    if (lane == 0) wred[wv] = c;
    __syncthreads();
    if (t < 64) pack_row_from_lds(rowbuf, node, t, dh, dl);
    if (t == 0) atomicAdd(&gacc[5], wred[0] + wred[1] + wred[2] + wred[3]);
}

// per-row scale: scale[r] = 1/sqrt(sum row^2 + eps)
__global__ __launch_bounds__(256) void k_cbscale(const float* __restrict__ cb, float* __restrict__ scale) {
    int row = blockIdx.x;
    float2 v = ((const float2*)(cb + (size_t)row * DD_))[threadIdx.x];
    float s = v.x * v.x + v.y * v.y;
    for (int off = 32; off; off >>= 1) s += __shfl_xor(s, off);
    __shared__ float wsum[4];
    int lane = threadIdx.x & 63, wv = threadIdx.x >> 6;
    if (lane == 0) wsum[wv] = s;
    __syncthreads();
    if (threadIdx.x == 0) scale[row] = 1.0f / sqrtf(wsum[0] + wsum[1] + wsum[2] + wsum[3] + 1e-12f);
}

// pack fp32 rows (opt gather + row-scale) into MFMA fragment order, bf16 hi/lo
__global__ __launch_bounds__(256) void k_pack(
    const float* __restrict__ src, const float* __restrict__ rowscale,
    const int* __restrict__ gidx, int nrows,
    unsigned short* __restrict__ dh, unsigned short* __restrict__ dl) {
    int u = threadIdx.x >> 6, lane = threadIdx.x & 63;
    int mt = blockIdx.x, kb = blockIdx.y * 4 + u;
    int gr = mt * 16 + (lane & 15);
    int k = kb * 32 + (lane >> 4) * 8;
    float vals[8] = {0.f,0.f,0.f,0.f,0.f,0.f,0.f,0.f};
    if (gr < nrows) {
        int row = gidx ? gidx[gr] : gr;
        float sc = rowscale ? rowscale[row] : 1.0f;
        const float4* p = (const float4*)(src + (size_t)row * DD_ + k);
        float4 a = p[0], b = p[1];
        vals[0]=a.x*sc; vals[1]=a.y*sc; vals[2]=a.z*sc; vals[3]=a.w*sc;
        vals[4]=b.x*sc; vals[5]=b.y*sc; vals[6]=b.z*sc; vals[7]=b.w*sc;
    }
    uint4 hw, lw;
    split8(vals, hw, lw);
    size_t base = (((size_t)mt * 16 + kb) * 64 + lane) * 8;
    *(uint4*)(dh + base) = hw;
    *(uint4*)(dl + base) = lw;
}

// transpose-pack a [512,512] weight: Bp rows = output cols
__global__ __launch_bounds__(256) void k_wpack(
    const float* __restrict__ W,
    unsigned short* __restrict__ dh, unsigned short* __restrict__ dl) {
    int u = threadIdx.x >> 6, lane = threadIdx.x & 63;
    int mt = blockIdx.x, kb = blockIdx.y * 4 + u;
    int n = mt * 16 + (lane & 15);
    int k = kb * 32 + (lane >> 4) * 8;
    float vals[8];
    #pragma unroll
    for (int j = 0; j < 8; ++j) vals[j] = W[(size_t)(k + j) * DD_ + n];
    uint4 hw, lw;
    split8(vals, hw, lw);
    size_t base = (((size_t)mt * 16 + kb) * 64 + lane) * 8;
    *(uint4*)(dh + base) = hw;
    *(uint4*)(dl + base) = lw;
}

// ---------------- MFMA GEMM, C = A . B^T via split-bf16 (hi/lo, 3 mfma) ----------
// MODE 0: dist — store C fp32 to Cout (stride KK_)
// MODE 1: rpass — upper-tri block grid, reduce sum/sumsq/min/max of symmetric C
// MODE 2: dense — store C+bias (opt relu) to Cout (stride DD_), rows < Mrows
// MODE 3: loss — accumulate sum((Ref - (C+bias))^2) into gacc[3]
template<int MODE>
__global__ __launch_bounds__(256) void gemm_mfma(
    const unsigned short* __restrict__ Ah, const unsigned short* __restrict__ Al,
    const unsigned short* __restrict__ Bh, const unsigned short* __restrict__ Bl,
    float* __restrict__ Cout, const float* __restrict__ bias,
    const float* __restrict__ Ref, int relu, int Mrows,
    float* __restrict__ gacc, u32* __restrict__ minKey, u32* __restrict__ maxKey) {
    if (MODE == 1 && blockIdx.x < blockIdx.y) return;  // bj >= bi only
    __shared__ char lds[32768];  // Ah|Al|Bh|Bl tiles, 8 KB each
    int tid = threadIdx.x;
    int wave = tid >> 6, lane = tid & 63;
    int gmtA = blockIdx.y * 8, gmtB = blockIdx.x * 8;
    const unsigned short* garr; int gmt0;
    if (wave == 0)      { garr = Ah; gmt0 = gmtA; }
    else if (wave == 1) { garr = Al; gmt0 = gmtA; }
    else if (wave == 2) { garr = Bh; gmt0 = gmtB; }
    else                { garr = Bl; gmt0 = gmtB; }
    char* ldst = lds + wave * 8192;
    f32x4 acc[4][4];
    #pragma unroll
    for (int i = 0; i < 4; ++i)
        #pragma unroll
        for (int j = 0; j < 4; ++j) acc[i][j] = (f32x4){0.f, 0.f, 0.f, 0.f};
    int wm = wave >> 1, wn = wave & 1;
    for (int kb = 0; kb < 16; ++kb) {
        #pragma unroll
        for (int t = 0; t < 8; ++t) {
            const char* g = (const char*)garr + (((size_t)(gmt0 + t) * 16 + kb) * 1024) + lane * 16;
            gld_lds16(ldst + t * 1024 + lane * 16, g);
        }
        __syncthreads();
        bf16x8 a_h[4], a_l[4], b_h[4], b_l[4];
        #pragma unroll
        for (int i = 0; i < 4; ++i) {
            int at = wm * 4 + i, bt = wn * 4 + i;
            a_h[i] = *(const bf16x8*)(lds + 0     + at * 1024 + lane * 16);
            a_l[i] = *(const bf16x8*)(lds + 8192  + at * 1024 + lane * 16);
            b_h[i] = *(const bf16x8*)(lds + 16384 + bt * 1024 + lane * 16);
            b_l[i] = *(const bf16x8*)(lds + 24576 + bt * 1024 + lane * 16);
        }
        #pragma unroll
        for (int i = 0; i < 4; ++i)
            #pragma unroll
            for (int j = 0; j < 4; ++j) {
                acc[i][j] = __builtin_amdgcn_mfma_f32_16x16x32_bf16(a_h[i], b_h[j], acc[i][j], 0, 0, 0);
                acc[i][j] = __builtin_amdgcn_mfma_f32_16x16x32_bf16(a_h[i], b_l[j], acc[i][j], 0, 0, 0);
                acc[i][j] = __builtin_amdgcn_mfma_f32_16x16x32_bf16(a_l[i], b_h[j], acc[i][j], 0, 0, 0);
            }
        __syncthreads();
    }
    // C/D layout: col = lane&15, row = (lane>>4)*4 + reg
    int m_base = blockIdx.y * 128 + wm * 64;
    int n_base = blockIdx.x * 128 + wn * 64;
    int rq = lane >> 4, cc = lane & 15;
    if (MODE == 0) {
        #pragma unroll
        for (int i = 0; i < 4; ++i) {
            int m = m_base + i * 16 + rq * 4;
            #pragma unroll
            for (int j = 0; j < 4; ++j) {
                int n = n_base + j * 16 + cc;
                #pragma unroll
                for (int r = 0; r < 4; ++r) {
                    if (m + r < NN_) Cout[(size_t)(m + r) * KK_ + n] = acc[i][j][r];
                }
            }
        }
    } else if (MODE == 2) {
        #pragma unroll
        for (int i = 0; i < 4; ++i) {
            int m = m_base + i * 16 + rq * 4;
            #pragma unroll
            for (int j = 0; j < 4; ++j) {
                int n = n_base + j * 16 + cc;
                float bv = bias[n];
                #pragma unroll
                for (int r = 0; r < 4; ++r) {
                    if (m + r < Mrows) {
                        float v = acc[i][j][r] + bv;
                        if (relu) v = fmaxf(v, 0.f);
                        Cout[(size_t)(m + r) * DD_ + n] = v;
                    }
                }
            }
        }
    } else if (MODE == 3) {
        float s = 0.f;
        #pragma unroll
        for (int i = 0; i < 4; ++i) {
            int m = m_base + i * 16 + rq * 4;
            #pragma unroll
            for (int j = 0; j < 4; ++j) {
                int n = n_base + j * 16 + cc;
                float bv = bias[n];
                #pragma unroll
                for (int r = 0; r < 4; ++r) {
                    if (m + r < Mrows) {
                        float d = Ref[(size_t)(m + r) * DD_ + n] - (acc[i][j][r] + bv);
                        s = fmaf(d, d, s);
                    }
                }
            }
        }
        float* red = (float*)lds;
        red[tid] = s; __syncthreads();
        for (int st = 128; st; st >>= 1) { if (tid < st) red[tid] += red[tid + st]; __syncthreads(); }
        if (tid == 0) atomicAdd(&gacc[3], red[0]);
    } else {
        float tsum = 0.f, tsq = 0.f, tmin = 3.4e38f, tmax = -3.4e38f;
        #pragma unroll
        for (int i = 0; i < 4; ++i) {
            #pragma unroll
            for (int j = 0; j < 4; ++j) {
                #pragma unroll
                for (int r = 0; r < 4; ++r) {
                    int m = m_base + i * 16 + rq * 4 + r;
                    int n = n_base + j * 16 + cc;
                    if (m < NN_ && n < NN_ && n >= m) {
                        float v = acc[i][j][r];
                        float w = (n > m) ? 2.f : 1.f;
                        tsum += w * v;
                        tsq  += w * v * v;
                        tmin = fminf(tmin, v);
                        tmax = fmaxf(tmax, v);
                    }
                }
            }
        }
        float* red = (float*)lds;
        red[tid] = tsum; __syncthreads();
        for (int s = 128; s; s >>= 1) { if (tid < s) red[tid] += red[tid + s]; __syncthreads(); }
        if (tid == 0) atomicAdd(&gacc[0], red[0]);
        __syncthreads();
        red[tid] = tsq; __syncthreads();
        for (int s = 128; s; s >>= 1) { if (tid < s) red[tid] += red[tid + s]; __syncthreads(); }
        if (tid == 0) atomicAdd(&gacc[1], red[0]);
        __syncthreads();
        red[tid] = tmin; __syncthreads();
        for (int s = 128; s; s >>= 1) { if (tid < s) red[tid] = fminf(red[tid], red[tid + s]); __syncthreads(); }
        if (tid == 0) atomicMin(minKey, okey(red[0]));
        __syncthreads();
        red[tid] = tmax; __syncthreads();
        for (int s = 128; s; s >>= 1) { if (tid < s) red[tid] = fmaxf(red[tid], red[tid + s]); __syncthreads(); }
        if (tid == 0) atomicMax(maxKey, okey(red[0]));
    }
}

// exact-fp32 argmax rescue (float4 dist reads)
__global__ __launch_bounds__(256) void k_rescore(
    const float* __restrict__ dist, const float* __restrict__ h,
    const float* __restrict__ rnorm, const float* __restrict__ cb,
    const float* __restrict__ scale, int* __restrict__ ind) {
    int row = blockIdx.x;
    const float4* dr4 = (const float4*)(dist + (size_t)row * KK_);
    int tid = threadIdx.x;
    float4 vbuf[4];
    float lmax = -3.4e38f;
    #pragma unroll
    for (int it = 0; it < 4; ++it) {
        float4 v = dr4[tid + it * 256];
        vbuf[it] = v;
        lmax = fmaxf(fmaxf(fmaxf(v.x, v.y), fmaxf(v.z, v.w)), lmax);
    }
    for (int off = 32; off; off >>= 1) lmax = fmaxf(lmax, __shfl_xor(lmax, off));
    __shared__ float wm4[4];
    __shared__ float bmax;
    __shared__ int cnt;
    __shared__ int cand[32];
    __shared__ u64 best;
    int lane = tid & 63, wv = tid >> 6;
    if (lane == 0) wm4[wv] = lmax;
    if (tid == 0) { cnt = 0; best = 0; }
    __syncthreads();
    if (tid == 0) bmax = fmaxf(fmaxf(wm4[0], wm4[1]), fmaxf(wm4[2], wm4[3]));
    __syncthreads();
    float thr = bmax - 1e-3f;
    #pragma unroll
    for (int it = 0; it < 4; ++it) {
        float4 v = vbuf[it];
        int cbase = (tid + it * 256) * 4;
        if (v.x >= thr) { int p = atomicAdd(&cnt, 1); if (p < 32) cand[p] = cbase + 0; }
        if (v.y >= thr) { int p = atomicAdd(&cnt, 1); if (p < 32) cand[p] = cbase + 1; }
        if (v.z >= thr) { int p = atomicAdd(&cnt, 1); if (p < 32) cand[p] = cbase + 2; }
        if (v.w >= thr) { int p = atomicAdd(&cnt, 1); if (p < 32) cand[p] = cbase + 3; }
    }
    __syncthreads();
    int nc = min(cnt, 32);
    float hr = rnorm[row];
    const float* hp = h + (size_t)row * DD_;
    for (int c = wv; c < nc; c += 4) {
        int col = cand[c];
        const float* cp = cb + (size_t)col * DD_;
        float dot = 0.f;
        #pragma unroll
        for (int j = 0; j < 8; ++j) dot = fmaf(hp[lane + j * 64], cp[lane + j * 64], dot);
        for (int off = 32; off; off >>= 1) dot += __shfl_xor(dot, off);
        if (lane == 0) atomicMax(&best, packKey(dot * hr * scale[col], col));
    }
    __syncthreads();
    if (tid == 0) ind[row] = (int)(~(u32)(best & 0xFFFFFFFFull));
}

// ---------------- fp32 GEMM (kept only for the 6000x40 output) ----------------
__global__ __launch_bounds__(256) void gemm_nn(
    const float* __restrict__ A, const float* __restrict__ B,
    const float* __restrict__ bias, float* __restrict__ C,
    int M, int Ncols, int Kdim) {
    __shared__ float As[16][68];
    __shared__ float Bs[16][68];
    int tid = threadIdx.x;
    int tx = tid & 15, ty = tid >> 4;
    int m0 = blockIdx.y * 64, n0 = blockIdx.x * 64;
    float cv[4][4] = {};
    int ar = tid >> 2;
    int ak = (tid & 3) << 2;
    int am = m0 + ar;
    const float* Arow = (am < M) ? (A + (size_t)am * Kdim) : nullptr;
    int bk = tid >> 4;
    int bn = (tid & 15) << 2;
    for (int k0 = 0; k0 < Kdim; k0 += 16) {
        float4 av = make_float4(0.f, 0.f, 0.f, 0.f);
        if (Arow) av = *(const float4*)(Arow + k0 + ak);
        As[ak + 0][ar] = av.x; As[ak + 1][ar] = av.y;
        As[ak + 2][ar] = av.z; As[ak + 3][ar] = av.w;
        float4 bv = make_float4(0.f, 0.f, 0.f, 0.f);
        if (n0 + bn < Ncols)
            bv = *(const float4*)(B + (size_t)(k0 + bk) * Ncols + n0 + bn);
        Bs[bk][bn + 0] = bv.x; Bs[bk][bn + 1] = bv.y;
        Bs[bk][bn + 2] = bv.z; Bs[bk][bn + 3] = bv.w;
        __syncthreads();
        #pragma unroll
        for (int kk = 0; kk < 16; ++kk) {
            float4 a4 = *(const float4*)&As[kk][ty << 2];
            float4 b4 = *(const float4*)&Bs[kk][tx << 2];
            float ax[4] = {a4.x, a4.y, a4.z, a4.w};
            float bx[4] = {b4.x, b4.y, b4.z, b4.w};
            #pragma unroll
            for (int i = 0; i < 4; ++i)
                #pragma unroll
                for (int j = 0; j < 4; ++j)
                    cv[i][j] = fmaf(ax[i], bx[j], cv[i][j]);
        }
        __syncthreads();
    }
    #pragma unroll
    for (int i = 0; i < 4; ++i) {
        int m = m0 + (ty << 2) + i;
        if (m >= M) continue;
        #pragma unroll
        for (int j = 0; j < 4; ++j) {
            int n = n0 + (tx << 2) + j;
            if (n >= Ncols) continue;
            C[(size_t)m * Ncols + n] = cv[i][j] + bias[n];
        }
    }
}

// ---------------- commit loss: sum (q - h)^2 ----------------
__global__ __launch_bounds__(256) void k_losses(
    const float* __restrict__ h, const float* __restrict__ cb,
    const float* __restrict__ scale, const int* __restrict__ ind,
    float* __restrict__ gacc) {
    float s1 = 0.f;
    for (int idx = blockIdx.x * 256 + threadIdx.x; idx < NN_ * DD_; idx += gridDim.x * 256) {
        int m = idx >> 9, d = idx & 511;
        int r = ind[m];
        float q = cb[(size_t)r * DD_ + d] * scale[r];
        float dq = q - h[idx];
        s1 = fmaf(dq, dq, s1);
    }
    for (int off = 32; off; off >>= 1) s1 += __shfl_xor(s1, off);
    __shared__ float w1[4];
    int lane = threadIdx.x & 63, wv = threadIdx.x >> 6;
    if (lane == 0) w1[wv] = s1;
    __syncthreads();
    if (threadIdx.x == 0) atomicAdd(&gacc[2], w1[0] + w1[1] + w1[2] + w1[3]);
}

// ---------------- edge multiplicity hash (for sum m^2 only) ----------------
__global__ void k_hash(const int* __restrict__ src, const int* __restrict__ dst,
                       int* __restrict__ hkey, int* __restrict__ hcnt) {
    int e = blockIdx.x * 256 + threadIdx.x;
    if (e >= EE_) return;
    int key = dst[e] * NN_ + src[e];
    u32 h = ((u32)key * 2654435761u) & HMASK;
    while (true) {
        int old = atomicCAS(&hkey[h], -1, key);
        if (old == -1 || old == key) { atomicAdd(&hcnt[h], 1); break; }
        h = (h + 1) & HMASK;
    }
}

__global__ __launch_bounds__(256) void k_m2scan(const int* __restrict__ hcnt, float* __restrict__ gacc) {
    float s = 0.f;
    for (int i = blockIdx.x * 256 + threadIdx.x; i < HSZ; i += gridDim.x * 256) {
        float c = (float)hcnt[i];
        s = fmaf(c, c, s);
    }
    for (int off = 32; off; off >>= 1) s += __shfl_xor(s, off);
    __shared__ float w1[4];
    int lane = threadIdx.x & 63, wv = threadIdx.x >> 6;
    if (lane == 0) w1[wv] = s;
    __syncthreads();
    if (threadIdx.x == 0) atomicAdd(&gacc[4], w1[0] + w1[1] + w1[2] + w1[3]);
}

// ---------------- final loss assembly ----------------
__global__ void k_final(const float* __restrict__ gacc, const u32* __restrict__ minKey,
                        const u32* __restrict__ maxKey, float* __restrict__ lossOut) {
    if (threadIdx.x != 0 || blockIdx.x != 0) return;
    double Rsum = gacc[0], Rsq = gacc[1], commitS = gacc[2], recS = gacc[3];
    double m2 = gacc[4], mr = gacc[5], ms = (double)EE_;
    double mn = (double)dkey(*minKey);
    double mx = (double)dkey(*maxKey);
    double den = mx - mn;
    double NN2 = (double)NN_ * (double)NN_;
    double sum_aq2 = (Rsq - 2.0 * mn * Rsum + NN2 * mn * mn) / (den * den);
    double sum_maq = (mr - mn * ms) / den;
    double total = sum_aq2 + m2 - 2.0 * sum_maq;
    double edge = sqrt(total / NN2);
    double commit = 0.25 * commitS / ((double)NN_ * (double)DD_);
    double rec = recS / ((double)NN_ * (double)DD_);
    *lossOut = (float)(rec + edge + commit);
}

extern "C" void kernel_launch(void* const* d_in, const int* in_sizes, int n_in,
                              void* d_out, int out_size, void* d_ws, size_t ws_size,
                              hipStream_t stream) {
    const float* feats = (const float*)d_in[0];
    const float* W1 = (const float*)d_in[1];
    const float* b1 = (const float*)d_in[2];
    const float* W2 = (const float*)d_in[3];
    const float* b2v = (const float*)d_in[4];
    const float* Wd1 = (const float*)d_in[5];
    const float* bd1 = (const float*)d_in[6];
    const float* Wd2 = (const float*)d_in[7];
    const float* bd2 = (const float*)d_in[8];
    const float* Wl = (const float*)d_in[9];
    const float* bl = (const float*)d_in[10];
    const float* cb = (const float*)d_in[11];
    const int* src = (const int*)d_in[12];
    const int* dst = (const int*)d_in[13];

    float* outF = (float*)d_out;
    float* lossOut = outF + (size_t)NN_ * OO_;     // element 240000
    float* distOut = lossOut + 1;                  // element 240001

    char* w = (char*)d_ws;
    size_t off = 0;
    auto alloc = [&](size_t bytes) -> void* {
        void* p = w + off;
        off = (off + bytes + 255) & ~(size_t)255;
        return p;
    };
    // zone0: zero-init
    float* gacc = (float*)alloc(64);
    u32* maxKey = (u32*)alloc(4);
    int* degin = (int*)alloc((size_t)NN_ * 4);
    int* degout = (int*)alloc((size_t)NN_ * 4);
    int* cursor = (int*)alloc((size_t)NN_ * 4);
    int* hcnt = (int*)alloc((size_t)HSZ * 4);
    size_t z0end = off;
    // zone1: 0xFF-init
    int* hkey = (int*)alloc((size_t)HSZ * 4);
    u32* minKey = (u32*)alloc(4);
    size_t z1end = off;
    // uninit scratch
    int* offs = (int*)alloc((size_t)(NN_ + 1) * 4);
    int* esrc = (int*)alloc((size_t)EE_ * 4);
    float* rin = (float*)alloc((size_t)NN_ * 4);
    float* rout = (float*)alloc((size_t)NN_ * 4);
    int* ind = (int*)alloc((size_t)NN_ * 4);
    float* scale = (float*)alloc((size_t)KK_ * 4);
    float* rnorm = (float*)alloc((size_t)NN_ * 4);
    float* h = (float*)alloc((size_t)NN_ * DD_ * 4);       // h, later h2
    float* QE = (float*)alloc((size_t)NN_ * DD_ * 4);
    const size_t NPACK = (size_t)MT_A * 16 * DD_;          // node-sized packed half
    unsigned short* P1 = (unsigned short*)alloc(NPACK * 2 * 2);  // aggp -> qcp -> agg2p
    unsigned short* P2 = (unsigned short*)alloc(NPACK * 2 * 2);  // hnp -> QEp
    unsigned short* enp = (unsigned short*)alloc((size_t)KK_ * DD_ * 2 * 2);
    const size_t WPACK = (size_t)32 * 16 * DD_;            // 512-row packed half
    unsigned short* W1p = (unsigned short*)alloc(WPACK * 2 * 2);
    unsigned short* Wd1p = (unsigned short*)alloc(WPACK * 2 * 2);
    unsigned short* Wd2p = (unsigned short*)alloc(WPACK * 2 * 2);
    unsigned short* W2p = (unsigned short*)alloc(WPACK * 2 * 2);

    unsigned short* aggp_h = P1,  *aggp_l = P1 + NPACK;
    unsigned short* qcp_h  = P1,  *qcp_l  = P1 + NPACK;
    unsigned short* ag2p_h = P1,  *ag2p_l = P1 + NPACK;
    unsigned short* hnp_h  = P2,  *hnp_l  = P2 + NPACK;
    unsigned short* QEp_h  = P2,  *QEp_l  = P2 + NPACK;
    unsigned short* enp_h  = enp, *enp_l  = enp + (size_t)KK_ * DD_;

    hipMemsetAsync(w, 0, z0end, stream);
    hipMemsetAsync(w + z0end, 0xFF, z1end - z0end, stream);

    const int TB = 256;
    k_deg<<<(EE_ + TB - 1) / TB, TB, 0, stream>>>(src, dst, degout, degin);
    k_rsqrtdeg<<<(NN_ + TB - 1) / TB, TB, 0, stream>>>(degout, degin, rout, rin);
    k_scan<<<1, 1024, 0, stream>>>(degin, offs, NN_);
    k_fill<<<(EE_ + TB - 1) / TB, TB, 0, stream>>>(src, dst, offs, cursor, esrc);
    k_wpack<<<dim3(32, 4), TB, 0, stream>>>(W1, W1p, W1p + WPACK);
    k_wpack<<<dim3(32, 4), TB, 0, stream>>>(Wd1, Wd1p, Wd1p + WPACK);
    k_wpack<<<dim3(32, 4), TB, 0, stream>>>(Wd2, Wd2p, Wd2p + WPACK);
    k_wpack<<<dim3(32, 4), TB, 0, stream>>>(W2, W2p, W2p + WPACK);
    k_aggp<<<NN_, TB, 0, stream>>>(feats, esrc, offs, rout, rin, aggp_h, aggp_l);
    gemm_mfma<2><<<dim3(4, NB_N), TB, 0, stream>>>(aggp_h, aggp_l, W1p, W1p + WPACK,
                                                   h, b1, nullptr, 1, NN_, nullptr, nullptr, nullptr);
    k_cbscale<<<NN_, TB, 0, stream>>>(h, rnorm);
    k_cbscale<<<KK_, TB, 0, stream>>>(cb, scale);
    k_pack<<<dim3(MT_A, 4), TB, 0, stream>>>(h, rnorm, nullptr, NN_, hnp_h, hnp_l);
    k_pack<<<dim3(KK_ / 16, 4), TB, 0, stream>>>(cb, scale, nullptr, KK_, enp_h, enp_l);
    gemm_mfma<0><<<dim3(KK_ / 128, NB_N), TB, 0, stream>>>(hnp_h, hnp_l, enp_h, enp_l,
                                                           distOut, nullptr, nullptr, 0, NN_,
                                                           nullptr, nullptr, nullptr);
    k_rescore<<<NN_, TB, 0, stream>>>(distOut, h, rnorm, cb, scale, ind);
    k_pack<<<dim3(MT_A, 4), TB, 0, stream>>>(cb, scale, ind, NN_, qcp_h, qcp_l);
    gemm_mfma<2><<<dim3(4, NB_N), TB, 0, stream>>>(qcp_h, qcp_l, Wd1p, Wd1p + WPACK,
                                                   QE, bd1, nullptr, 0, NN_, nullptr, nullptr, nullptr);
    gemm_mfma<3><<<dim3(4, NB_N), TB, 0, stream>>>(qcp_h, qcp_l, Wd2p, Wd2p + WPACK,
                                                   nullptr, bd2, h, 0, NN_, gacc, nullptr, nullptr);
    k_losses<<<2048, TB, 0, stream>>>(h, cb, scale, ind, gacc);
    k_pack<<<dim3(MT_A, 4), TB, 0, stream>>>(QE, nullptr, nullptr, NN_, QEp_h, QEp_l);
    gemm_mfma<1><<<dim3(NB_N, NB_N), TB, 0, stream>>>(QEp_h, QEp_l, QEp_h, QEp_l,
                                                      nullptr, nullptr, nullptr, 0, NN_,
                                                      gacc, minKey, maxKey);
    k_hash<<<(EE_ + TB - 1) / TB, TB, 0, stream>>>(src, dst, hkey, hcnt);
    k_m2scan<<<512, TB, 0, stream>>>(hcnt, gacc);
    k_aggd<<<NN_, TB, 0, stream>>>(QE, esrc, offs, rout, rin, ag2p_h, ag2p_l, gacc);
    gemm_mfma<2><<<dim3(4, NB_N), TB, 0, stream>>>(ag2p_h, ag2p_l, W2p, W2p + WPACK,
                                                   h, b2v, nullptr, 1, NN_, nullptr, nullptr, nullptr);
    gemm_nn<<<dim3(1, 94), TB, 0, stream>>>(h, Wl, bl, outF, NN_, OO_, DD_);
    k_final<<<1, 64, 0, stream>>>(gacc, minKey, maxKey, lossOut);
}